// Round 1
// baseline (760.774 us; speedup 1.0000x reference)
//
#include <hip/hip_runtime.h>

#define DIM 96
#define DIM4 (DIM/4)

// ---------------- degree / norm ----------------

__global__ void init_deg_kernel(float* __restrict__ deg, int n) {
    int i = blockIdx.x * blockDim.x + threadIdx.x;
    if (i < n) deg[i] = 1.0f;   // self-loop weight
}

__global__ void edge_deg_kernel(const int* __restrict__ col, const float* __restrict__ ew,
                                float* __restrict__ deg, int e) {
    int i = blockIdx.x * blockDim.x + threadIdx.x;
    if (i < e) atomicAdd(&deg[col[i]], ew[i]);
}

__global__ void to_dinv_kernel(float* __restrict__ deg, int n) {
    int i = blockIdx.x * blockDim.x + threadIdx.x;
    if (i < n) deg[i] = rsqrtf(deg[i]);   // deg >= 1 always
}

// ---------------- GEMM: H = X @ W  (X: n x 96, W: 96 x 96) ----------------

__global__ __launch_bounds__(256) void gemm96_kernel(const float* __restrict__ X,
                                                     const float* __restrict__ W,
                                                     float* __restrict__ H, int n) {
    __shared__ float Ws[DIM * DIM];   // 36 KB
    for (int i = threadIdx.x; i < DIM * DIM; i += 256) Ws[i] = W[i];
    __syncthreads();

    int idx = blockIdx.x * 256 + threadIdx.x;
    int r = idx / DIM;
    int c = idx - r * DIM;
    if (r >= n) return;

    const float* xr = X + (size_t)r * DIM;
    float acc = 0.0f;
#pragma unroll
    for (int k = 0; k < DIM; ++k)
        acc = fmaf(xr[k], Ws[k * DIM + c], acc);
    H[idx] = acc;
}

// ---------------- scatter: agg[col] += norm * H[row]  (one wave per edge) ----------------

__global__ __launch_bounds__(256) void scatter_kernel(const int* __restrict__ row,
                                                      const int* __restrict__ col,
                                                      const float* __restrict__ ew,
                                                      const float* __restrict__ dinv,
                                                      const float* __restrict__ H,
                                                      float* __restrict__ agg, int e) {
    int wid  = threadIdx.x >> 6;
    int lane = threadIdx.x & 63;
    int ei = blockIdx.x * 4 + wid;
    if (ei >= e) return;

    int r = row[ei];
    int c = col[ei];
    float nrm = dinv[r] * ew[ei] * dinv[c];

    const float* hr = H   + (size_t)r * DIM;
    float*       ar = agg + (size_t)c * DIM;
#pragma unroll
    for (int d = lane; d < DIM; d += 64)
        atomicAdd(&ar[d], hr[d] * nrm);
}

// ---------------- finalize: out = relu(agg + H*dinv^2 + b)  (float4 over n*24) ----------------

__global__ __launch_bounds__(256) void finalize_kernel(const float* __restrict__ agg,
                                                       const float* __restrict__ H,
                                                       const float* __restrict__ dinv,
                                                       const float* __restrict__ bias,
                                                       float* __restrict__ out, int n) {
    int idx = blockIdx.x * 256 + threadIdx.x;
    int total = n * DIM4;
    if (idx >= total) return;
    int r = idx / DIM4;
    int q = idx - r * DIM4;

    float di = dinv[r];
    float s  = di * di;

    float4 a = ((const float4*)agg)[idx];
    float4 h = ((const float4*)H)[idx];
    float4 b = ((const float4*)bias)[q];

    float4 o;
    o.x = fmaxf(a.x + h.x * s + b.x, 0.0f);
    o.y = fmaxf(a.y + h.y * s + b.y, 0.0f);
    o.z = fmaxf(a.z + h.z * s + b.z, 0.0f);
    o.w = fmaxf(a.w + h.w * s + b.w, 0.0f);
    ((float4*)out)[idx] = o;
}

// ---------------- launch ----------------

extern "C" void kernel_launch(void* const* d_in, const int* in_sizes, int n_in,
                              void* d_out, int out_size, void* d_ws, size_t ws_size,
                              hipStream_t stream) {
    const float* x   = (const float*)d_in[0];
    const int*   ei  = (const int*)d_in[1];
    const float* ew  = (const float*)d_in[2];
    // d_in[3] = batch (unused)
    const float* W1  = (const float*)d_in[4];
    const float* b1  = (const float*)d_in[5];
    const float* W2  = (const float*)d_in[6];
    const float* b2  = (const float*)d_in[7];

    const int N = in_sizes[0] / DIM;
    const int E = in_sizes[1] / 2;
    const int* row = ei;
    const int* col = ei + E;

    char* ws = (char*)d_ws;
    float* dinv = (float*)ws;                                   // N floats
    size_t off = ((size_t)N * 4 + 255) & ~(size_t)255;
    float* A = (float*)(ws + off);                              // N*DIM floats (h)
    float* B = (float*)(ws + off + (size_t)N * DIM * 4);        // N*DIM floats (agg1 / y1)
    float* out = (float*)d_out;

    const size_t ND_bytes = (size_t)N * DIM * 4;

    dim3 blk(256);
    int gN   = (N + 255) / 256;
    int gE   = (E + 255) / 256;
    int gMM  = (N * DIM + 255) / 256;
    int gSc  = (E + 3) / 4;
    int gFin = (N * DIM4 + 255) / 256;

    // degree -> dinv (shared by both layers)
    init_deg_kernel<<<gN, blk, 0, stream>>>(dinv, N);
    edge_deg_kernel<<<gE, blk, 0, stream>>>(col, ew, dinv, E);
    to_dinv_kernel<<<gN, blk, 0, stream>>>(dinv, N);

    // ---- layer 1 ----
    gemm96_kernel<<<gMM, blk, 0, stream>>>(x, W1, A, N);
    hipMemsetAsync(B, 0, ND_bytes, stream);
    scatter_kernel<<<gSc, blk, 0, stream>>>(row, col, ew, dinv, A, B, E);
    finalize_kernel<<<gFin, blk, 0, stream>>>(B, A, dinv, b1, B, N);   // y1 in B

    // ---- layer 2 ----
    gemm96_kernel<<<gMM, blk, 0, stream>>>(B, W2, A, N);
    hipMemsetAsync(out, 0, ND_bytes, stream);
    scatter_kernel<<<gSc, blk, 0, stream>>>(row, col, ew, dinv, A, out, E);
    finalize_kernel<<<gFin, blk, 0, stream>>>(out, A, dinv, b2, out, N);
}

// Round 2
// 500.364 us; speedup vs baseline: 1.5204x; 1.5204x over previous
//
#include <hip/hip_runtime.h>

#define DIM 96
#define DIM4 (DIM/4)

// ---------------- init: deg = 1.0 (self-loop), cnt = 0 ----------------

__global__ void init_kernel(float* __restrict__ deg, int* __restrict__ cnt, int n) {
    int i = blockIdx.x * blockDim.x + threadIdx.x;
    if (i < n) { deg[i] = 1.0f; cnt[i] = 0; }
}

// ---------------- per-edge: weighted degree + in-degree histogram ----------------

__global__ void edge_deg_kernel(const int* __restrict__ col, const float* __restrict__ ew,
                                float* __restrict__ deg, int* __restrict__ cnt, int e) {
    int i = blockIdx.x * blockDim.x + threadIdx.x;
    if (i < e) {
        int c = col[i];
        atomicAdd(&deg[c], ew[i]);
        atomicAdd(&cnt[c], 1);
    }
}

__global__ void to_dinv_kernel(float* __restrict__ deg, int n) {
    int i = blockIdx.x * blockDim.x + threadIdx.x;
    if (i < n) deg[i] = rsqrtf(deg[i]);   // deg >= 1 always
}

// ---------------- single-workgroup exclusive scan: cnt -> rowptr, cursor ----------------

__global__ __launch_bounds__(1024) void scan_kernel(const int* __restrict__ cnt,
                                                    int* __restrict__ rowptr,
                                                    int* __restrict__ cursor, int n) {
    __shared__ int smem[1024];
    __shared__ int carry_s;
    if (threadIdx.x == 0) carry_s = 0;
    __syncthreads();
    for (int base = 0; base < n; base += 1024) {
        int i = base + (int)threadIdx.x;
        int v = (i < n) ? cnt[i] : 0;
        smem[threadIdx.x] = v;
        __syncthreads();
        // Hillis-Steele inclusive scan
        for (int off = 1; off < 1024; off <<= 1) {
            int t = (threadIdx.x >= (unsigned)off) ? smem[threadIdx.x - off] : 0;
            __syncthreads();
            smem[threadIdx.x] += t;
            __syncthreads();
        }
        int incl = smem[threadIdx.x];
        int carry = carry_s;
        if (i < n) {
            int rp = carry + incl - v;   // exclusive
            rowptr[i] = rp;
            cursor[i] = rp;
        }
        __syncthreads();
        if (threadIdx.x == 1023) carry_s = carry + smem[1023];
        __syncthreads();
    }
    if (threadIdx.x == 0) rowptr[n] = carry_s;
}

// ---------------- fill CSR: srow[p]=row, sval[p]=ew*dinv[row] ----------------

__global__ void fill_kernel(const int* __restrict__ row, const int* __restrict__ col,
                            const float* __restrict__ ew, const float* __restrict__ dinv,
                            int* __restrict__ cursor, int* __restrict__ srow,
                            float* __restrict__ sval, int e) {
    int i = blockIdx.x * blockDim.x + threadIdx.x;
    if (i < e) {
        int c = col[i];
        int r = row[i];
        int p = atomicAdd(&cursor[c], 1);
        srow[p] = r;
        sval[p] = ew[i] * dinv[r];
    }
}

// ---------------- GEMM: H = X @ W  (X: n x 96, W: 96 x 96) ----------------

__global__ __launch_bounds__(256) void gemm96_kernel(const float* __restrict__ X,
                                                     const float* __restrict__ W,
                                                     float* __restrict__ H, int n) {
    __shared__ float Ws[DIM * DIM];   // 36 KB
    for (int i = threadIdx.x; i < DIM * DIM; i += 256) Ws[i] = W[i];
    __syncthreads();

    int idx = blockIdx.x * 256 + threadIdx.x;
    int r = idx / DIM;
    int c = idx - r * DIM;
    if (r >= n) return;

    const float4* xr = (const float4*)(X + (size_t)r * DIM);
    float acc = 0.0f;
#pragma unroll
    for (int k4 = 0; k4 < DIM4; ++k4) {
        float4 xv = xr[k4];
        acc = fmaf(xv.x, Ws[(k4 * 4 + 0) * DIM + c], acc);
        acc = fmaf(xv.y, Ws[(k4 * 4 + 1) * DIM + c], acc);
        acc = fmaf(xv.z, Ws[(k4 * 4 + 2) * DIM + c], acc);
        acc = fmaf(xv.w, Ws[(k4 * 4 + 3) * DIM + c], acc);
    }
    H[idx] = acc;
}

// ---------------- fused gather + self-loop + bias + relu ----------------
// 24 threads per node (each owns one float4 chunk), 8 nodes per 192-thread block.

#define NPB 8

__global__ __launch_bounds__(192) void gather_kernel(const int* __restrict__ rowptr,
                                                     const int* __restrict__ srow,
                                                     const float* __restrict__ sval,
                                                     const float* __restrict__ dinv,
                                                     const float* __restrict__ H,
                                                     const float* __restrict__ bias,
                                                     float* __restrict__ out, int n) {
    int ln = threadIdx.x / 24;
    int q  = threadIdx.x - ln * 24;
    int node = blockIdx.x * NPB + ln;
    if (node >= n) return;

    int beg = rowptr[node];
    int end = rowptr[node + 1];
    float di = dinv[node];

    float4 acc = make_float4(0.f, 0.f, 0.f, 0.f);
    for (int p = beg; p < end; ++p) {
        int r = srow[p];
        float w = sval[p] * di;
        float4 h = ((const float4*)(H + (size_t)r * DIM))[q];
        acc.x = fmaf(w, h.x, acc.x);
        acc.y = fmaf(w, h.y, acc.y);
        acc.z = fmaf(w, h.z, acc.z);
        acc.w = fmaf(w, h.w, acc.w);
    }

    float s = di * di;
    float4 hc = ((const float4*)(H + (size_t)node * DIM))[q];
    float4 b  = ((const float4*)bias)[q];

    float4 o;
    o.x = fmaxf(fmaf(hc.x, s, acc.x) + b.x, 0.0f);
    o.y = fmaxf(fmaf(hc.y, s, acc.y) + b.y, 0.0f);
    o.z = fmaxf(fmaf(hc.z, s, acc.z) + b.z, 0.0f);
    o.w = fmaxf(fmaf(hc.w, s, acc.w) + b.w, 0.0f);
    ((float4*)(out + (size_t)node * DIM))[q] = o;
}

// ---------------- launch ----------------

extern "C" void kernel_launch(void* const* d_in, const int* in_sizes, int n_in,
                              void* d_out, int out_size, void* d_ws, size_t ws_size,
                              hipStream_t stream) {
    const float* x   = (const float*)d_in[0];
    const int*   ei  = (const int*)d_in[1];
    const float* ew  = (const float*)d_in[2];
    // d_in[3] = batch (unused)
    const float* W1  = (const float*)d_in[4];
    const float* b1  = (const float*)d_in[5];
    const float* W2  = (const float*)d_in[6];
    const float* b2  = (const float*)d_in[7];

    const int N = in_sizes[0] / DIM;
    const int E = in_sizes[1] / 2;
    const int* row = ei;
    const int* col = ei + E;

    // workspace layout (all 256B-aligned)
    char* ws = (char*)d_ws;
    size_t off = 0;
    auto alloc = [&](size_t bytes) { void* p = ws + off; off = (off + bytes + 255) & ~(size_t)255; return p; };
    float* dinv   = (float*)alloc((size_t)N * 4);
    int*   cnt    = (int*)  alloc((size_t)N * 4);        // histogram (dead after scan)
    int*   rowptr = (int*)  alloc((size_t)(N + 1) * 4);
    int*   cursor = (int*)  alloc((size_t)N * 4);
    int*   srow   = (int*)  alloc((size_t)E * 4);
    float* sval   = (float*)alloc((size_t)E * 4);
    float* A      = (float*)alloc((size_t)N * DIM * 4);  // H buffer
    float* out    = (float*)d_out;

    dim3 blk(256);
    int gN  = (N + 255) / 256;
    int gE  = (E + 255) / 256;
    int gMM = (N * DIM + 255) / 256;
    int gG  = (N + NPB - 1) / NPB;

    // ---- CSR build (once, shared by both layers) ----
    init_kernel<<<gN, blk, 0, stream>>>(dinv, cnt, N);
    edge_deg_kernel<<<gE, blk, 0, stream>>>(col, ew, dinv, cnt, E);
    to_dinv_kernel<<<gN, blk, 0, stream>>>(dinv, N);
    scan_kernel<<<1, 1024, 0, stream>>>(cnt, rowptr, cursor, N);
    fill_kernel<<<gE, blk, 0, stream>>>(row, col, ew, dinv, cursor, srow, sval, E);

    // ---- layer 1 ----  (y1 goes into d_out as scratch)
    gemm96_kernel<<<gMM, blk, 0, stream>>>(x, W1, A, N);
    gather_kernel<<<gG, 192, 0, stream>>>(rowptr, srow, sval, dinv, A, b1, out, N);

    // ---- layer 2 ----
    gemm96_kernel<<<gMM, blk, 0, stream>>>(out, W2, A, N);
    gather_kernel<<<gG, 192, 0, stream>>>(rowptr, srow, sval, dinv, A, b2, out, N);
}

// Round 3
// 402.691 us; speedup vs baseline: 1.8892x; 1.2426x over previous
//
#include <hip/hip_runtime.h>

#define DIM 96
#define DIM4 (DIM/4)

// ---------------- init: deg = 1.0 (self-loop), cnt = 0 ----------------

__global__ void init_kernel(float* __restrict__ deg, int* __restrict__ cnt, int n) {
    int i = blockIdx.x * blockDim.x + threadIdx.x;
    if (i < n) { deg[i] = 1.0f; cnt[i] = 0; }
}

// ---------------- per-edge: weighted degree + in-degree histogram ----------------

__global__ void edge_deg_kernel(const int* __restrict__ col, const float* __restrict__ ew,
                                float* __restrict__ deg, int* __restrict__ cnt, int e) {
    int i = blockIdx.x * blockDim.x + threadIdx.x;
    if (i < e) {
        int c = col[i];
        atomicAdd(&deg[c], ew[i]);
        atomicAdd(&cnt[c], 1);
    }
}

__global__ void to_dinv_kernel(float* __restrict__ deg, int n) {
    int i = blockIdx.x * blockDim.x + threadIdx.x;
    if (i < n) deg[i] = rsqrtf(deg[i]);   // deg >= 1 always
}

// ---------------- single-workgroup exclusive scan: cnt -> rowptr, cursor ----------------

__global__ __launch_bounds__(1024) void scan_kernel(const int* __restrict__ cnt,
                                                    int* __restrict__ rowptr,
                                                    int* __restrict__ cursor, int n) {
    __shared__ int smem[1024];
    __shared__ int carry_s;
    if (threadIdx.x == 0) carry_s = 0;
    __syncthreads();
    for (int base = 0; base < n; base += 1024) {
        int i = base + (int)threadIdx.x;
        int v = (i < n) ? cnt[i] : 0;
        smem[threadIdx.x] = v;
        __syncthreads();
        // Hillis-Steele inclusive scan
        for (int off = 1; off < 1024; off <<= 1) {
            int t = (threadIdx.x >= (unsigned)off) ? smem[threadIdx.x - off] : 0;
            __syncthreads();
            smem[threadIdx.x] += t;
            __syncthreads();
        }
        int incl = smem[threadIdx.x];
        int carry = carry_s;
        if (i < n) {
            int rp = carry + incl - v;   // exclusive
            rowptr[i] = rp;
            cursor[i] = rp;
        }
        __syncthreads();
        if (threadIdx.x == 1023) carry_s = carry + smem[1023];
        __syncthreads();
    }
    if (threadIdx.x == 0) rowptr[n] = carry_s;
}

// ---------------- fill CSR: srow[p]=row, sval[p]=ew*dinv[row] ----------------

__global__ void fill_kernel(const int* __restrict__ row, const int* __restrict__ col,
                            const float* __restrict__ ew, const float* __restrict__ dinv,
                            int* __restrict__ cursor, int* __restrict__ srow,
                            float* __restrict__ sval, int e) {
    int i = blockIdx.x * blockDim.x + threadIdx.x;
    if (i < e) {
        int c = col[i];
        int r = row[i];
        int p = atomicAdd(&cursor[c], 1);
        srow[p] = r;
        sval[p] = ew[i] * dinv[r];
    }
}

// ---------------- GEMM: H = X @ W  (X: n x 96, W: 96 x 96) ----------------
// Register-blocked: 2 threads per row, each computes 48 cols (12 float4 acc).
// Per 8-k chunk: 2 float4 x-loads (reused 48x), W via broadcast ds_read_b128.

__global__ __launch_bounds__(256) void gemm96_kernel(const float* __restrict__ X,
                                                     const float* __restrict__ W,
                                                     float* __restrict__ H, int n) {
    __shared__ float Ws[DIM * DIM];   // 36 KB
    for (int i = threadIdx.x; i < DIM * DIM; i += 256) Ws[i] = W[i];
    __syncthreads();

    int half = threadIdx.x & 1;            // which 48-col half
    int r = blockIdx.x * 128 + (threadIdx.x >> 1);
    if (r >= n) return;

    const float4* xp = (const float4*)(X + (size_t)r * DIM);

    float4 acc[12];
#pragma unroll
    for (int i = 0; i < 12; ++i) acc[i] = make_float4(0.f, 0.f, 0.f, 0.f);

#pragma unroll 1
    for (int kb = 0; kb < 12; ++kb) {
        float4 x0 = xp[2 * kb];
        float4 x1 = xp[2 * kb + 1];
        const float* wk = &Ws[(kb * 8) * DIM + half * 48];
#pragma unroll
        for (int j = 0; j < 8; ++j) {
            float xv = (j == 0) ? x0.x : (j == 1) ? x0.y : (j == 2) ? x0.z : (j == 3) ? x0.w
                     : (j == 4) ? x1.x : (j == 5) ? x1.y : (j == 6) ? x1.z : x1.w;
            const float4* wrow = (const float4*)(wk + j * DIM);
#pragma unroll
            for (int cb = 0; cb < 12; ++cb) {
                float4 w = wrow[cb];
                acc[cb].x = fmaf(xv, w.x, acc[cb].x);
                acc[cb].y = fmaf(xv, w.y, acc[cb].y);
                acc[cb].z = fmaf(xv, w.z, acc[cb].z);
                acc[cb].w = fmaf(xv, w.w, acc[cb].w);
            }
        }
    }

    float4* hp = (float4*)(H + (size_t)r * DIM + half * 48);
#pragma unroll
    for (int cb = 0; cb < 12; ++cb) hp[cb] = acc[cb];
}

// ---------------- fused gather + self-loop + bias + relu ----------------
// 24 threads per node (each owns one float4 chunk), 8 nodes per 192-thread block.

#define NPB 8

__global__ __launch_bounds__(192) void gather_kernel(const int* __restrict__ rowptr,
                                                     const int* __restrict__ srow,
                                                     const float* __restrict__ sval,
                                                     const float* __restrict__ dinv,
                                                     const float* __restrict__ H,
                                                     const float* __restrict__ bias,
                                                     float* __restrict__ out, int n) {
    int ln = threadIdx.x / 24;
    int q  = threadIdx.x - ln * 24;
    int node = blockIdx.x * NPB + ln;
    if (node >= n) return;

    int beg = rowptr[node];
    int end = rowptr[node + 1];
    float di = dinv[node];

    float4 acc = make_float4(0.f, 0.f, 0.f, 0.f);
    for (int p = beg; p < end; ++p) {
        int r = srow[p];
        float w = sval[p] * di;
        float4 h = ((const float4*)(H + (size_t)r * DIM))[q];
        acc.x = fmaf(w, h.x, acc.x);
        acc.y = fmaf(w, h.y, acc.y);
        acc.z = fmaf(w, h.z, acc.z);
        acc.w = fmaf(w, h.w, acc.w);
    }

    float s = di * di;
    float4 hc = ((const float4*)(H + (size_t)node * DIM))[q];
    float4 b  = ((const float4*)bias)[q];

    float4 o;
    o.x = fmaxf(fmaf(hc.x, s, acc.x) + b.x, 0.0f);
    o.y = fmaxf(fmaf(hc.y, s, acc.y) + b.y, 0.0f);
    o.z = fmaxf(fmaf(hc.z, s, acc.z) + b.z, 0.0f);
    o.w = fmaxf(fmaf(hc.w, s, acc.w) + b.w, 0.0f);
    ((float4*)(out + (size_t)node * DIM))[q] = o;
}

// ---------------- launch ----------------

extern "C" void kernel_launch(void* const* d_in, const int* in_sizes, int n_in,
                              void* d_out, int out_size, void* d_ws, size_t ws_size,
                              hipStream_t stream) {
    const float* x   = (const float*)d_in[0];
    const int*   ei  = (const int*)d_in[1];
    const float* ew  = (const float*)d_in[2];
    // d_in[3] = batch (unused)
    const float* W1  = (const float*)d_in[4];
    const float* b1  = (const float*)d_in[5];
    const float* W2  = (const float*)d_in[6];
    const float* b2  = (const float*)d_in[7];

    const int N = in_sizes[0] / DIM;
    const int E = in_sizes[1] / 2;
    const int* row = ei;
    const int* col = ei + E;

    // workspace layout (all 256B-aligned)
    char* ws = (char*)d_ws;
    size_t off = 0;
    auto alloc = [&](size_t bytes) { void* p = ws + off; off = (off + bytes + 255) & ~(size_t)255; return p; };
    float* dinv   = (float*)alloc((size_t)N * 4);
    int*   cnt    = (int*)  alloc((size_t)N * 4);        // histogram (dead after scan)
    int*   rowptr = (int*)  alloc((size_t)(N + 1) * 4);
    int*   cursor = (int*)  alloc((size_t)N * 4);
    int*   srow   = (int*)  alloc((size_t)E * 4);
    float* sval   = (float*)alloc((size_t)E * 4);
    float* A      = (float*)alloc((size_t)N * DIM * 4);  // H buffer
    float* out    = (float*)d_out;

    dim3 blk(256);
    int gN  = (N + 255) / 256;
    int gE  = (E + 255) / 256;
    int gMM = (N + 127) / 128;          // 128 rows per block (2 threads/row)
    int gG  = (N + NPB - 1) / NPB;

    // ---- CSR build (once, shared by both layers) ----
    init_kernel<<<gN, blk, 0, stream>>>(dinv, cnt, N);
    edge_deg_kernel<<<gE, blk, 0, stream>>>(col, ew, dinv, cnt, E);
    to_dinv_kernel<<<gN, blk, 0, stream>>>(dinv, N);
    scan_kernel<<<1, 1024, 0, stream>>>(cnt, rowptr, cursor, N);
    fill_kernel<<<gE, blk, 0, stream>>>(row, col, ew, dinv, cursor, srow, sval, E);

    // ---- layer 1 ----  (y1 goes into d_out as scratch)
    gemm96_kernel<<<gMM, blk, 0, stream>>>(x, W1, A, N);
    gather_kernel<<<gG, 192, 0, stream>>>(rowptr, srow, sval, dinv, A, b1, out, N);

    // ---- layer 2 ----
    gemm96_kernel<<<gMM, blk, 0, stream>>>(out, W2, A, N);
    gather_kernel<<<gG, 192, 0, stream>>>(rowptr, srow, sval, dinv, A, b2, out, N);
}

// Round 4
// 319.357 us; speedup vs baseline: 2.3822x; 1.2609x over previous
//
#include <hip/hip_runtime.h>

#define DIM 96
#define DIM4 (DIM/4)

// ---------------- init: deg = 1.0 (self-loop), cnt = 0 ----------------

__global__ void init_kernel(float* __restrict__ deg, int* __restrict__ cnt, int n) {
    int i = blockIdx.x * blockDim.x + threadIdx.x;
    if (i < n) { deg[i] = 1.0f; cnt[i] = 0; }
}

// ---------------- per-edge: weighted degree + in-degree histogram ----------------

__global__ void edge_deg_kernel(const int* __restrict__ col, const float* __restrict__ ew,
                                float* __restrict__ deg, int* __restrict__ cnt, int e) {
    int i = blockIdx.x * blockDim.x + threadIdx.x;
    if (i < e) {
        int c = col[i];
        atomicAdd(&deg[c], ew[i]);
        atomicAdd(&cnt[c], 1);
    }
}

__global__ void to_dinv_kernel(float* __restrict__ deg, int n) {
    int i = blockIdx.x * blockDim.x + threadIdx.x;
    if (i < n) deg[i] = rsqrtf(deg[i]);   // deg >= 1 always
}

// ---------------- 3-phase multi-block exclusive scan: cnt -> rowptr, cursor ----------------
// 1024 elements per block.

#define SCAN_BLK 256
#define SCAN_ELEMS 1024

__global__ __launch_bounds__(SCAN_BLK) void scan_phaseA(const int* __restrict__ cnt,
                                                        int* __restrict__ bsum, int n) {
    __shared__ int sdata[SCAN_BLK];
    int base = blockIdx.x * SCAN_ELEMS;
    int s = 0;
#pragma unroll
    for (int j = 0; j < 4; ++j) {
        int i = base + j * SCAN_BLK + (int)threadIdx.x;
        if (i < n) s += cnt[i];
    }
    sdata[threadIdx.x] = s;
    __syncthreads();
    for (int off = SCAN_BLK / 2; off > 0; off >>= 1) {
        if (threadIdx.x < (unsigned)off) sdata[threadIdx.x] += sdata[threadIdx.x + off];
        __syncthreads();
    }
    if (threadIdx.x == 0) bsum[blockIdx.x] = sdata[0];
}

// single block: exclusive-scan bsum[0..nb) in place, write total to rowptr[n]
__global__ __launch_bounds__(1024) void scan_phaseB(int* __restrict__ bsum,
                                                    int* __restrict__ rowptr, int nb, int n) {
    __shared__ int sdata[1024];
    int v = (threadIdx.x < (unsigned)nb) ? bsum[threadIdx.x] : 0;
    sdata[threadIdx.x] = v;
    __syncthreads();
    for (int off = 1; off < 1024; off <<= 1) {
        int t = (threadIdx.x >= (unsigned)off) ? sdata[threadIdx.x - off] : 0;
        __syncthreads();
        sdata[threadIdx.x] += t;
        __syncthreads();
    }
    if (threadIdx.x < (unsigned)nb) bsum[threadIdx.x] = sdata[threadIdx.x] - v;  // exclusive
    if (threadIdx.x == (unsigned)(nb - 1)) rowptr[n] = sdata[threadIdx.x];       // total
}

__global__ __launch_bounds__(SCAN_BLK) void scan_phaseC(const int* __restrict__ cnt,
                                                        const int* __restrict__ bsum,
                                                        int* __restrict__ rowptr,
                                                        int* __restrict__ cursor, int n) {
    __shared__ int sdata[SCAN_BLK];
    int base = blockIdx.x * SCAN_ELEMS + (int)threadIdx.x * 4;
    int v[4];
#pragma unroll
    for (int j = 0; j < 4; ++j) v[j] = (base + j < n) ? cnt[base + j] : 0;
    int tsum = v[0] + v[1] + v[2] + v[3];
    sdata[threadIdx.x] = tsum;
    __syncthreads();
    for (int off = 1; off < SCAN_BLK; off <<= 1) {
        int t = (threadIdx.x >= (unsigned)off) ? sdata[threadIdx.x - off] : 0;
        __syncthreads();
        sdata[threadIdx.x] += t;
        __syncthreads();
    }
    int excl = bsum[blockIdx.x] + sdata[threadIdx.x] - tsum;
#pragma unroll
    for (int j = 0; j < 4; ++j) {
        if (base + j < n) { rowptr[base + j] = excl; cursor[base + j] = excl; }
        excl += v[j];
    }
}

// ---------------- fill CSR: srow[p]=row, sval[p]=ew*dinv[row] ----------------

__global__ void fill_kernel(const int* __restrict__ row, const int* __restrict__ col,
                            const float* __restrict__ ew, const float* __restrict__ dinv,
                            int* __restrict__ cursor, int* __restrict__ srow,
                            float* __restrict__ sval, int e) {
    int i = blockIdx.x * blockDim.x + threadIdx.x;
    if (i < e) {
        int c = col[i];
        int r = row[i];
        int p = atomicAdd(&cursor[c], 1);
        srow[p] = r;
        sval[p] = ew[i] * dinv[r];
    }
}

// ---------------- GEMM: H = X @ W  (X: n x 96, W: 96 x 96) ----------------
// Register-blocked: 2 threads per row, each computes 48 cols (12 float4 acc).

__global__ __launch_bounds__(256) void gemm96_kernel(const float* __restrict__ X,
                                                     const float* __restrict__ W,
                                                     float* __restrict__ H, int n) {
    __shared__ float Ws[DIM * DIM];   // 36 KB
    for (int i = threadIdx.x; i < DIM * DIM; i += 256) Ws[i] = W[i];
    __syncthreads();

    int half = threadIdx.x & 1;            // which 48-col half
    int r = blockIdx.x * 128 + (threadIdx.x >> 1);
    if (r >= n) return;

    const float4* xp = (const float4*)(X + (size_t)r * DIM);

    float4 acc[12];
#pragma unroll
    for (int i = 0; i < 12; ++i) acc[i] = make_float4(0.f, 0.f, 0.f, 0.f);

#pragma unroll 1
    for (int kb = 0; kb < 12; ++kb) {
        float4 x0 = xp[2 * kb];
        float4 x1 = xp[2 * kb + 1];
        const float* wk = &Ws[(kb * 8) * DIM + half * 48];
#pragma unroll
        for (int j = 0; j < 8; ++j) {
            float xv = (j == 0) ? x0.x : (j == 1) ? x0.y : (j == 2) ? x0.z : (j == 3) ? x0.w
                     : (j == 4) ? x1.x : (j == 5) ? x1.y : (j == 6) ? x1.z : x1.w;
            const float4* wrow = (const float4*)(wk + j * DIM);
#pragma unroll
            for (int cb = 0; cb < 12; ++cb) {
                float4 w = wrow[cb];
                acc[cb].x = fmaf(xv, w.x, acc[cb].x);
                acc[cb].y = fmaf(xv, w.y, acc[cb].y);
                acc[cb].z = fmaf(xv, w.z, acc[cb].z);
                acc[cb].w = fmaf(xv, w.w, acc[cb].w);
            }
        }
    }

    float4* hp = (float4*)(H + (size_t)r * DIM + half * 48);
#pragma unroll
    for (int cb = 0; cb < 12; ++cb) hp[cb] = acc[cb];
}

// ---------------- fused gather + self-loop + bias + relu ----------------
// 24 threads per node (each owns one float4 chunk), 8 nodes per 192-thread block.

#define NPB 8

__global__ __launch_bounds__(192) void gather_kernel(const int* __restrict__ rowptr,
                                                     const int* __restrict__ srow,
                                                     const float* __restrict__ sval,
                                                     const float* __restrict__ dinv,
                                                     const float* __restrict__ H,
                                                     const float* __restrict__ bias,
                                                     float* __restrict__ out, int n) {
    int ln = threadIdx.x / 24;
    int q  = threadIdx.x - ln * 24;
    int node = blockIdx.x * NPB + ln;
    if (node >= n) return;

    int beg = rowptr[node];
    int end = rowptr[node + 1];
    float di = dinv[node];

    float4 acc = make_float4(0.f, 0.f, 0.f, 0.f);
    for (int p = beg; p < end; ++p) {
        int r = srow[p];
        float w = sval[p] * di;
        float4 h = ((const float4*)(H + (size_t)r * DIM))[q];
        acc.x = fmaf(w, h.x, acc.x);
        acc.y = fmaf(w, h.y, acc.y);
        acc.z = fmaf(w, h.z, acc.z);
        acc.w = fmaf(w, h.w, acc.w);
    }

    float s = di * di;
    float4 hc = ((const float4*)(H + (size_t)node * DIM))[q];
    float4 b  = ((const float4*)bias)[q];

    float4 o;
    o.x = fmaxf(fmaf(hc.x, s, acc.x) + b.x, 0.0f);
    o.y = fmaxf(fmaf(hc.y, s, acc.y) + b.y, 0.0f);
    o.z = fmaxf(fmaf(hc.z, s, acc.z) + b.z, 0.0f);
    o.w = fmaxf(fmaf(hc.w, s, acc.w) + b.w, 0.0f);
    ((float4*)(out + (size_t)node * DIM))[q] = o;
}

// ---------------- launch ----------------

extern "C" void kernel_launch(void* const* d_in, const int* in_sizes, int n_in,
                              void* d_out, int out_size, void* d_ws, size_t ws_size,
                              hipStream_t stream) {
    const float* x   = (const float*)d_in[0];
    const int*   ei  = (const int*)d_in[1];
    const float* ew  = (const float*)d_in[2];
    // d_in[3] = batch (unused)
    const float* W1  = (const float*)d_in[4];
    const float* b1  = (const float*)d_in[5];
    const float* W2  = (const float*)d_in[6];
    const float* b2  = (const float*)d_in[7];

    const int N = in_sizes[0] / DIM;
    const int E = in_sizes[1] / 2;
    const int* row = ei;
    const int* col = ei + E;

    const int NB = (N + SCAN_ELEMS - 1) / SCAN_ELEMS;   // scan blocks (49 for N=50000)

    // workspace layout (all 256B-aligned)
    char* ws = (char*)d_ws;
    size_t off = 0;
    auto alloc = [&](size_t bytes) { void* p = ws + off; off = (off + bytes + 255) & ~(size_t)255; return p; };
    float* dinv   = (float*)alloc((size_t)N * 4);
    int*   cnt    = (int*)  alloc((size_t)N * 4);
    int*   rowptr = (int*)  alloc((size_t)(N + 1) * 4);
    int*   cursor = (int*)  alloc((size_t)N * 4);
    int*   bsum   = (int*)  alloc((size_t)NB * 4);
    int*   srow   = (int*)  alloc((size_t)E * 4);
    float* sval   = (float*)alloc((size_t)E * 4);
    float* A      = (float*)alloc((size_t)N * DIM * 4);  // H buffer
    float* out    = (float*)d_out;

    dim3 blk(256);
    int gN  = (N + 255) / 256;
    int gE  = (E + 255) / 256;
    int gMM = (N + 127) / 128;          // 128 rows per block (2 threads/row)
    int gG  = (N + NPB - 1) / NPB;

    // ---- CSR build (once, shared by both layers) ----
    init_kernel<<<gN, blk, 0, stream>>>(dinv, cnt, N);
    edge_deg_kernel<<<gE, blk, 0, stream>>>(col, ew, dinv, cnt, E);
    to_dinv_kernel<<<gN, blk, 0, stream>>>(dinv, N);
    scan_phaseA<<<NB, SCAN_BLK, 0, stream>>>(cnt, bsum, N);
    scan_phaseB<<<1, 1024, 0, stream>>>(bsum, rowptr, NB, N);
    scan_phaseC<<<NB, SCAN_BLK, 0, stream>>>(cnt, bsum, rowptr, cursor, N);
    fill_kernel<<<gE, blk, 0, stream>>>(row, col, ew, dinv, cursor, srow, sval, E);

    // ---- layer 1 ----  (y1 goes into d_out as scratch)
    gemm96_kernel<<<gMM, blk, 0, stream>>>(x, W1, A, N);
    gather_kernel<<<gG, 192, 0, stream>>>(rowptr, srow, sval, dinv, A, b1, out, N);

    // ---- layer 2 ----
    gemm96_kernel<<<gMM, blk, 0, stream>>>(out, W2, A, N);
    gather_kernel<<<gG, 192, 0, stream>>>(rowptr, srow, sval, dinv, A, b2, out, N);
}

// Round 5
// 272.057 us; speedup vs baseline: 2.7964x; 1.1739x over previous
//
#include <hip/hip_runtime.h>
#include <hip/hip_fp16.h>

#define DIM 96
#define DIM4 (DIM/4)

// ---------------- per-edge: packed (count<<32 | fixed-point weight) histogram ----------------
// weight scale 2^22; max weighted in-degree << 64 so low word stays < 2^28: no carry into count.

#define WSCALE 4194304.0f   // 2^22

__global__ void edge_pack_kernel(const int* __restrict__ col, const float* __restrict__ ew,
                                 unsigned long long* __restrict__ pdeg, int e) {
    int i = blockIdx.x * blockDim.x + threadIdx.x;
    if (i < e) {
        unsigned q = (unsigned)(ew[i] * WSCALE + 0.5f);
        atomicAdd(&pdeg[col[i]], (1ULL << 32) | (unsigned long long)q);
    }
}

// unpack: dinv = rsqrt(1 + wsum), cnt = count
__global__ void to_dinv_kernel(const unsigned long long* __restrict__ pdeg,
                               float* __restrict__ dinv, int* __restrict__ cnt, int n) {
    int i = blockIdx.x * blockDim.x + threadIdx.x;
    if (i < n) {
        unsigned long long p = pdeg[i];
        cnt[i] = (int)(p >> 32);
        float deg = 1.0f + (float)(p & 0xffffffffULL) * (1.0f / WSCALE);
        dinv[i] = rsqrtf(deg);
    }
}

// ---------------- 3-phase multi-block exclusive scan: cnt -> rowptr, cursor ----------------

#define SCAN_BLK 256
#define SCAN_ELEMS 1024

__global__ __launch_bounds__(SCAN_BLK) void scan_phaseA(const int* __restrict__ cnt,
                                                        int* __restrict__ bsum, int n) {
    __shared__ int sdata[SCAN_BLK];
    int base = blockIdx.x * SCAN_ELEMS;
    int s = 0;
#pragma unroll
    for (int j = 0; j < 4; ++j) {
        int i = base + j * SCAN_BLK + (int)threadIdx.x;
        if (i < n) s += cnt[i];
    }
    sdata[threadIdx.x] = s;
    __syncthreads();
    for (int off = SCAN_BLK / 2; off > 0; off >>= 1) {
        if (threadIdx.x < (unsigned)off) sdata[threadIdx.x] += sdata[threadIdx.x + off];
        __syncthreads();
    }
    if (threadIdx.x == 0) bsum[blockIdx.x] = sdata[0];
}

__global__ __launch_bounds__(1024) void scan_phaseB(int* __restrict__ bsum,
                                                    int* __restrict__ rowptr, int nb, int n) {
    __shared__ int sdata[1024];
    int v = (threadIdx.x < (unsigned)nb) ? bsum[threadIdx.x] : 0;
    sdata[threadIdx.x] = v;
    __syncthreads();
    for (int off = 1; off < 1024; off <<= 1) {
        int t = (threadIdx.x >= (unsigned)off) ? sdata[threadIdx.x - off] : 0;
        __syncthreads();
        sdata[threadIdx.x] += t;
        __syncthreads();
    }
    if (threadIdx.x < (unsigned)nb) bsum[threadIdx.x] = sdata[threadIdx.x] - v;  // exclusive
    if (threadIdx.x == (unsigned)(nb - 1)) rowptr[n] = sdata[threadIdx.x];       // total
}

__global__ __launch_bounds__(SCAN_BLK) void scan_phaseC(const int* __restrict__ cnt,
                                                        const int* __restrict__ bsum,
                                                        int* __restrict__ rowptr,
                                                        int* __restrict__ cursor, int n) {
    __shared__ int sdata[SCAN_BLK];
    int base = blockIdx.x * SCAN_ELEMS + (int)threadIdx.x * 4;
    int v[4];
#pragma unroll
    for (int j = 0; j < 4; ++j) v[j] = (base + j < n) ? cnt[base + j] : 0;
    int tsum = v[0] + v[1] + v[2] + v[3];
    sdata[threadIdx.x] = tsum;
    __syncthreads();
    for (int off = 1; off < SCAN_BLK; off <<= 1) {
        int t = (threadIdx.x >= (unsigned)off) ? sdata[threadIdx.x - off] : 0;
        __syncthreads();
        sdata[threadIdx.x] += t;
        __syncthreads();
    }
    int excl = bsum[blockIdx.x] + sdata[threadIdx.x] - tsum;
#pragma unroll
    for (int j = 0; j < 4; ++j) {
        if (base + j < n) { rowptr[base + j] = excl; cursor[base + j] = excl; }
        excl += v[j];
    }
}

// ---------------- fill CSR: srow[p]=row, sval[p]=ew*dinv[row] ----------------

__global__ void fill_kernel(const int* __restrict__ row, const int* __restrict__ col,
                            const float* __restrict__ ew, const float* __restrict__ dinv,
                            int* __restrict__ cursor, int* __restrict__ srow,
                            float* __restrict__ sval, int e) {
    int i = blockIdx.x * blockDim.x + threadIdx.x;
    if (i < e) {
        int c = col[i];
        int r = row[i];
        int p = atomicAdd(&cursor[c], 1);
        srow[p] = r;
        sval[p] = ew[i] * dinv[r];
    }
}

// ---------------- GEMM: H = X @ W, H stored fp16  ----------------
// Register-blocked: 2 threads per row, each computes 48 cols (12 float4 acc).

__global__ __launch_bounds__(256) void gemm96_kernel(const float* __restrict__ X,
                                                     const float* __restrict__ W,
                                                     __half* __restrict__ H, int n) {
    __shared__ float Ws[DIM * DIM];   // 36 KB
    for (int i = threadIdx.x; i < DIM * DIM; i += 256) Ws[i] = W[i];
    __syncthreads();

    int half_ = threadIdx.x & 1;           // which 48-col half
    int r = blockIdx.x * 128 + (threadIdx.x >> 1);
    if (r >= n) return;

    const float4* xp = (const float4*)(X + (size_t)r * DIM);

    float4 acc[12];
#pragma unroll
    for (int i = 0; i < 12; ++i) acc[i] = make_float4(0.f, 0.f, 0.f, 0.f);

#pragma unroll 1
    for (int kb = 0; kb < 12; ++kb) {
        float4 x0 = xp[2 * kb];
        float4 x1 = xp[2 * kb + 1];
        const float* wk = &Ws[(kb * 8) * DIM + half_ * 48];
#pragma unroll
        for (int j = 0; j < 8; ++j) {
            float xv = (j == 0) ? x0.x : (j == 1) ? x0.y : (j == 2) ? x0.z : (j == 3) ? x0.w
                     : (j == 4) ? x1.x : (j == 5) ? x1.y : (j == 6) ? x1.z : x1.w;
            const float4* wrow = (const float4*)(wk + j * DIM);
#pragma unroll
            for (int cb = 0; cb < 12; ++cb) {
                float4 w = wrow[cb];
                acc[cb].x = fmaf(xv, w.x, acc[cb].x);
                acc[cb].y = fmaf(xv, w.y, acc[cb].y);
                acc[cb].z = fmaf(xv, w.z, acc[cb].z);
                acc[cb].w = fmaf(xv, w.w, acc[cb].w);
            }
        }
    }

    uint2* hp = (uint2*)(H + (size_t)r * DIM + half_ * 48);
#pragma unroll
    for (int cb = 0; cb < 12; ++cb) {
        __half2 lo = __float22half2_rn(make_float2(acc[cb].x, acc[cb].y));
        __half2 hi = __float22half2_rn(make_float2(acc[cb].z, acc[cb].w));
        uint2 u;
        u.x = *(const unsigned*)&lo;
        u.y = *(const unsigned*)&hi;
        hp[cb] = u;
    }
}

// ---------------- fused gather + self-loop + bias + relu (H in fp16) ----------------
// 24 threads per node (each owns 4 features = 8 bytes), 8 nodes per 192-thread block.

#define NPB 8

__device__ __forceinline__ float4 half4_to_float4(uint2 hv) {
    __half2 h01 = *(const __half2*)&hv.x;
    __half2 h23 = *(const __half2*)&hv.y;
    float2 f01 = __half22float2(h01);
    float2 f23 = __half22float2(h23);
    return make_float4(f01.x, f01.y, f23.x, f23.y);
}

__global__ __launch_bounds__(192) void gather_kernel(const int* __restrict__ rowptr,
                                                     const int* __restrict__ srow,
                                                     const float* __restrict__ sval,
                                                     const float* __restrict__ dinv,
                                                     const __half* __restrict__ H,
                                                     const float* __restrict__ bias,
                                                     float* __restrict__ out, int n) {
    int ln = threadIdx.x / 24;
    int q  = threadIdx.x - ln * 24;
    int node = blockIdx.x * NPB + ln;
    if (node >= n) return;

    int beg = rowptr[node];
    int end = rowptr[node + 1];
    float di = dinv[node];

    float4 acc = make_float4(0.f, 0.f, 0.f, 0.f);
    int p = beg;
    for (; p + 1 < end; p += 2) {
        int r0 = srow[p];
        int r1 = srow[p + 1];
        float w0 = sval[p] * di;
        float w1 = sval[p + 1] * di;
        uint2 hv0 = ((const uint2*)(H + (size_t)r0 * DIM))[q];
        uint2 hv1 = ((const uint2*)(H + (size_t)r1 * DIM))[q];
        float4 h0 = half4_to_float4(hv0);
        float4 h1 = half4_to_float4(hv1);
        acc.x = fmaf(w0, h0.x, acc.x); acc.y = fmaf(w0, h0.y, acc.y);
        acc.z = fmaf(w0, h0.z, acc.z); acc.w = fmaf(w0, h0.w, acc.w);
        acc.x = fmaf(w1, h1.x, acc.x); acc.y = fmaf(w1, h1.y, acc.y);
        acc.z = fmaf(w1, h1.z, acc.z); acc.w = fmaf(w1, h1.w, acc.w);
    }
    if (p < end) {
        int r0 = srow[p];
        float w0 = sval[p] * di;
        float4 h0 = half4_to_float4(((const uint2*)(H + (size_t)r0 * DIM))[q]);
        acc.x = fmaf(w0, h0.x, acc.x); acc.y = fmaf(w0, h0.y, acc.y);
        acc.z = fmaf(w0, h0.z, acc.z); acc.w = fmaf(w0, h0.w, acc.w);
    }

    float s = di * di;
    float4 hc = half4_to_float4(((const uint2*)(H + (size_t)node * DIM))[q]);
    float4 b  = ((const float4*)bias)[q];

    float4 o;
    o.x = fmaxf(fmaf(hc.x, s, acc.x) + b.x, 0.0f);
    o.y = fmaxf(fmaf(hc.y, s, acc.y) + b.y, 0.0f);
    o.z = fmaxf(fmaf(hc.z, s, acc.z) + b.z, 0.0f);
    o.w = fmaxf(fmaf(hc.w, s, acc.w) + b.w, 0.0f);
    ((float4*)(out + (size_t)node * DIM))[q] = o;
}

// ---------------- launch ----------------

extern "C" void kernel_launch(void* const* d_in, const int* in_sizes, int n_in,
                              void* d_out, int out_size, void* d_ws, size_t ws_size,
                              hipStream_t stream) {
    const float* x   = (const float*)d_in[0];
    const int*   ei  = (const int*)d_in[1];
    const float* ew  = (const float*)d_in[2];
    // d_in[3] = batch (unused)
    const float* W1  = (const float*)d_in[4];
    const float* b1  = (const float*)d_in[5];
    const float* W2  = (const float*)d_in[6];
    const float* b2  = (const float*)d_in[7];

    const int N = in_sizes[0] / DIM;
    const int E = in_sizes[1] / 2;
    const int* row = ei;
    const int* col = ei + E;

    const int NB = (N + SCAN_ELEMS - 1) / SCAN_ELEMS;

    // workspace layout (all 256B-aligned)
    char* ws = (char*)d_ws;
    size_t off = 0;
    auto alloc = [&](size_t bytes) { void* p = ws + off; off = (off + bytes + 255) & ~(size_t)255; return p; };
    unsigned long long* pdeg = (unsigned long long*)alloc((size_t)N * 8);
    float* dinv   = (float*)alloc((size_t)N * 4);
    int*   cnt    = (int*)  alloc((size_t)N * 4);
    int*   rowptr = (int*)  alloc((size_t)(N + 1) * 4);
    int*   cursor = (int*)  alloc((size_t)N * 4);
    int*   bsum   = (int*)  alloc((size_t)NB * 4);
    int*   srow   = (int*)  alloc((size_t)E * 4);
    float* sval   = (float*)alloc((size_t)E * 4);
    __half* A     = (__half*)alloc((size_t)N * DIM * 2);   // H buffer (fp16)
    float* out    = (float*)d_out;

    dim3 blk(256);
    int gN  = (N + 255) / 256;
    int gE  = (E + 255) / 256;
    int gMM = (N + 127) / 128;          // 128 rows per block (2 threads/row)
    int gG  = (N + NPB - 1) / NPB;

    // ---- CSR build (once, shared by both layers) ----
    hipMemsetAsync(pdeg, 0, (size_t)N * 8, stream);
    edge_pack_kernel<<<gE, blk, 0, stream>>>(col, ew, pdeg, E);
    to_dinv_kernel<<<gN, blk, 0, stream>>>(pdeg, dinv, cnt, N);
    scan_phaseA<<<NB, SCAN_BLK, 0, stream>>>(cnt, bsum, N);
    scan_phaseB<<<1, 1024, 0, stream>>>(bsum, rowptr, NB, N);
    scan_phaseC<<<NB, SCAN_BLK, 0, stream>>>(cnt, bsum, rowptr, cursor, N);
    fill_kernel<<<gE, blk, 0, stream>>>(row, col, ew, dinv, cursor, srow, sval, E);

    // ---- layer 1 ----  (y1 goes into d_out as scratch)
    gemm96_kernel<<<gMM, blk, 0, stream>>>(x, W1, A, N);
    gather_kernel<<<gG, 192, 0, stream>>>(rowptr, srow, sval, dinv, A, b1, out, N);

    // ---- layer 2 ----
    gemm96_kernel<<<gMM, blk, 0, stream>>>(out, W2, A, N);
    gather_kernel<<<gG, 192, 0, stream>>>(rowptr, srow, sval, dinv, A, b2, out, N);
}

// Round 6
// 224.670 us; speedup vs baseline: 3.3862x; 1.2109x over previous
//
#include <hip/hip_runtime.h>
#include <hip/hip_fp16.h>

#define DIM 96
#define DIM4 (DIM/4)

// ---------------- per-edge: packed (count<<32 | fixed-point weight) histogram ----------------
// weight scale 2^22; max weighted in-degree << 64 so low word stays < 2^28: no carry into count.
// The atomic RETURN's high word is this edge's rank within its destination segment -> saved,
// it replaces the cursor atomic in fill.

#define WSCALE 4194304.0f   // 2^22

__global__ void edge_pack_kernel(const int* __restrict__ col, const float* __restrict__ ew,
                                 unsigned long long* __restrict__ pdeg,
                                 int* __restrict__ rank, int e) {
    int i = blockIdx.x * blockDim.x + threadIdx.x;
    if (i < e) {
        unsigned q = (unsigned)(ew[i] * WSCALE + 0.5f);
        unsigned long long old =
            atomicAdd(&pdeg[col[i]], (1ULL << 32) | (unsigned long long)q);
        rank[i] = (int)(old >> 32);
    }
}

// unpack: dinv = rsqrt(1 + wsum), cnt = count
__global__ void to_dinv_kernel(const unsigned long long* __restrict__ pdeg,
                               float* __restrict__ dinv, int* __restrict__ cnt, int n) {
    int i = blockIdx.x * blockDim.x + threadIdx.x;
    if (i < n) {
        unsigned long long p = pdeg[i];
        cnt[i] = (int)(p >> 32);
        float deg = 1.0f + (float)(p & 0xffffffffULL) * (1.0f / WSCALE);
        dinv[i] = rsqrtf(deg);
    }
}

// ---------------- 3-phase multi-block exclusive scan: cnt -> rowptr ----------------

#define SCAN_BLK 256
#define SCAN_ELEMS 1024

__global__ __launch_bounds__(SCAN_BLK) void scan_phaseA(const int* __restrict__ cnt,
                                                        int* __restrict__ bsum, int n) {
    __shared__ int sdata[SCAN_BLK];
    int base = blockIdx.x * SCAN_ELEMS;
    int s = 0;
#pragma unroll
    for (int j = 0; j < 4; ++j) {
        int i = base + j * SCAN_BLK + (int)threadIdx.x;
        if (i < n) s += cnt[i];
    }
    sdata[threadIdx.x] = s;
    __syncthreads();
    for (int off = SCAN_BLK / 2; off > 0; off >>= 1) {
        if (threadIdx.x < (unsigned)off) sdata[threadIdx.x] += sdata[threadIdx.x + off];
        __syncthreads();
    }
    if (threadIdx.x == 0) bsum[blockIdx.x] = sdata[0];
}

__global__ __launch_bounds__(1024) void scan_phaseB(int* __restrict__ bsum,
                                                    int* __restrict__ rowptr, int nb, int n) {
    __shared__ int sdata[1024];
    int v = (threadIdx.x < (unsigned)nb) ? bsum[threadIdx.x] : 0;
    sdata[threadIdx.x] = v;
    __syncthreads();
    for (int off = 1; off < 1024; off <<= 1) {
        int t = (threadIdx.x >= (unsigned)off) ? sdata[threadIdx.x - off] : 0;
        __syncthreads();
        sdata[threadIdx.x] += t;
        __syncthreads();
    }
    if (threadIdx.x < (unsigned)nb) bsum[threadIdx.x] = sdata[threadIdx.x] - v;  // exclusive
    if (threadIdx.x == (unsigned)(nb - 1)) rowptr[n] = sdata[threadIdx.x];       // total
}

__global__ __launch_bounds__(SCAN_BLK) void scan_phaseC(const int* __restrict__ cnt,
                                                        const int* __restrict__ bsum,
                                                        int* __restrict__ rowptr, int n) {
    __shared__ int sdata[SCAN_BLK];
    int base = blockIdx.x * SCAN_ELEMS + (int)threadIdx.x * 4;
    int v[4];
#pragma unroll
    for (int j = 0; j < 4; ++j) v[j] = (base + j < n) ? cnt[base + j] : 0;
    int tsum = v[0] + v[1] + v[2] + v[3];
    sdata[threadIdx.x] = tsum;
    __syncthreads();
    for (int off = 1; off < SCAN_BLK; off <<= 1) {
        int t = (threadIdx.x >= (unsigned)off) ? sdata[threadIdx.x - off] : 0;
        __syncthreads();
        sdata[threadIdx.x] += t;
        __syncthreads();
    }
    int excl = bsum[blockIdx.x] + sdata[threadIdx.x] - tsum;
#pragma unroll
    for (int j = 0; j < 4; ++j) {
        if (base + j < n) rowptr[base + j] = excl;
        excl += v[j];
    }
}

// ---------------- fill CSR (atomic-free): spack[rowptr[col]+rank] = {row, ew*dinv[row]} ----------------

__global__ void fill_kernel(const int* __restrict__ row, const int* __restrict__ col,
                            const float* __restrict__ ew, const float* __restrict__ dinv,
                            const int* __restrict__ rowptr, const int* __restrict__ rank,
                            int2* __restrict__ spack, int e) {
    int i = blockIdx.x * blockDim.x + threadIdx.x;
    if (i < e) {
        int c = col[i];
        int r = row[i];
        int p = rowptr[c] + rank[i];
        spack[p] = make_int2(r, __float_as_int(ew[i] * dinv[r]));
    }
}

// ---------------- GEMM: H = X @ W, H stored fp16  ----------------
// Register-blocked: 2 threads per row, each computes 48 cols (12 float4 acc).

__global__ __launch_bounds__(256) void gemm96_kernel(const float* __restrict__ X,
                                                     const float* __restrict__ W,
                                                     __half* __restrict__ H, int n) {
    __shared__ float Ws[DIM * DIM];   // 36 KB
    for (int i = threadIdx.x; i < DIM * DIM; i += 256) Ws[i] = W[i];
    __syncthreads();

    int half_ = threadIdx.x & 1;           // which 48-col half
    int r = blockIdx.x * 128 + (threadIdx.x >> 1);
    if (r >= n) return;

    const float4* xp = (const float4*)(X + (size_t)r * DIM);

    float4 acc[12];
#pragma unroll
    for (int i = 0; i < 12; ++i) acc[i] = make_float4(0.f, 0.f, 0.f, 0.f);

#pragma unroll 1
    for (int kb = 0; kb < 12; ++kb) {
        float4 x0 = xp[2 * kb];
        float4 x1 = xp[2 * kb + 1];
        const float* wk = &Ws[(kb * 8) * DIM + half_ * 48];
#pragma unroll
        for (int j = 0; j < 8; ++j) {
            float xv = (j == 0) ? x0.x : (j == 1) ? x0.y : (j == 2) ? x0.z : (j == 3) ? x0.w
                     : (j == 4) ? x1.x : (j == 5) ? x1.y : (j == 6) ? x1.z : x1.w;
            const float4* wrow = (const float4*)(wk + j * DIM);
#pragma unroll
            for (int cb = 0; cb < 12; ++cb) {
                float4 w = wrow[cb];
                acc[cb].x = fmaf(xv, w.x, acc[cb].x);
                acc[cb].y = fmaf(xv, w.y, acc[cb].y);
                acc[cb].z = fmaf(xv, w.z, acc[cb].z);
                acc[cb].w = fmaf(xv, w.w, acc[cb].w);
            }
        }
    }

    uint2* hp = (uint2*)(H + (size_t)r * DIM + half_ * 48);
#pragma unroll
    for (int cb = 0; cb < 12; ++cb) {
        __half2 lo = __float22half2_rn(make_float2(acc[cb].x, acc[cb].y));
        __half2 hi = __float22half2_rn(make_float2(acc[cb].z, acc[cb].w));
        uint2 u;
        u.x = *(const unsigned*)&lo;
        u.y = *(const unsigned*)&hi;
        hp[cb] = u;
    }
}

// ---------------- fused gather + self-loop + bias + relu (H in fp16) ----------------
// 24 threads per node (each owns 4 features = 8 bytes), 8 nodes per 192-thread block.

#define NPB 8

__device__ __forceinline__ float4 half4_to_float4(uint2 hv) {
    __half2 h01 = *(const __half2*)&hv.x;
    __half2 h23 = *(const __half2*)&hv.y;
    float2 f01 = __half22float2(h01);
    float2 f23 = __half22float2(h23);
    return make_float4(f01.x, f01.y, f23.x, f23.y);
}

__global__ __launch_bounds__(192) void gather_kernel(const int* __restrict__ rowptr,
                                                     const int2* __restrict__ spack,
                                                     const float* __restrict__ dinv,
                                                     const __half* __restrict__ H,
                                                     const float* __restrict__ bias,
                                                     float* __restrict__ out, int n) {
    int ln = threadIdx.x / 24;
    int q  = threadIdx.x - ln * 24;
    int node = blockIdx.x * NPB + ln;
    if (node >= n) return;

    int beg = rowptr[node];
    int end = rowptr[node + 1];
    float di = dinv[node];

    float4 acc = make_float4(0.f, 0.f, 0.f, 0.f);
    int p = beg;
    for (; p + 1 < end; p += 2) {
        int2 e0 = spack[p];
        int2 e1 = spack[p + 1];
        float w0 = __int_as_float(e0.y) * di;
        float w1 = __int_as_float(e1.y) * di;
        uint2 hv0 = ((const uint2*)(H + (size_t)e0.x * DIM))[q];
        uint2 hv1 = ((const uint2*)(H + (size_t)e1.x * DIM))[q];
        float4 h0 = half4_to_float4(hv0);
        float4 h1 = half4_to_float4(hv1);
        acc.x = fmaf(w0, h0.x, acc.x); acc.y = fmaf(w0, h0.y, acc.y);
        acc.z = fmaf(w0, h0.z, acc.z); acc.w = fmaf(w0, h0.w, acc.w);
        acc.x = fmaf(w1, h1.x, acc.x); acc.y = fmaf(w1, h1.y, acc.y);
        acc.z = fmaf(w1, h1.z, acc.z); acc.w = fmaf(w1, h1.w, acc.w);
    }
    if (p < end) {
        int2 e0 = spack[p];
        float w0 = __int_as_float(e0.y) * di;
        float4 h0 = half4_to_float4(((const uint2*)(H + (size_t)e0.x * DIM))[q]);
        acc.x = fmaf(w0, h0.x, acc.x); acc.y = fmaf(w0, h0.y, acc.y);
        acc.z = fmaf(w0, h0.z, acc.z); acc.w = fmaf(w0, h0.w, acc.w);
    }

    float s = di * di;
    float4 hc = half4_to_float4(((const uint2*)(H + (size_t)node * DIM))[q]);
    float4 b  = ((const float4*)bias)[q];

    float4 o;
    o.x = fmaxf(fmaf(hc.x, s, acc.x) + b.x, 0.0f);
    o.y = fmaxf(fmaf(hc.y, s, acc.y) + b.y, 0.0f);
    o.z = fmaxf(fmaf(hc.z, s, acc.z) + b.z, 0.0f);
    o.w = fmaxf(fmaf(hc.w, s, acc.w) + b.w, 0.0f);
    ((float4*)(out + (size_t)node * DIM))[q] = o;
}

// ---------------- launch ----------------

extern "C" void kernel_launch(void* const* d_in, const int* in_sizes, int n_in,
                              void* d_out, int out_size, void* d_ws, size_t ws_size,
                              hipStream_t stream) {
    const float* x   = (const float*)d_in[0];
    const int*   ei  = (const int*)d_in[1];
    const float* ew  = (const float*)d_in[2];
    // d_in[3] = batch (unused)
    const float* W1  = (const float*)d_in[4];
    const float* b1  = (const float*)d_in[5];
    const float* W2  = (const float*)d_in[6];
    const float* b2  = (const float*)d_in[7];

    const int N = in_sizes[0] / DIM;
    const int E = in_sizes[1] / 2;
    const int* row = ei;
    const int* col = ei + E;

    const int NB = (N + SCAN_ELEMS - 1) / SCAN_ELEMS;

    // workspace layout (all 256B-aligned)
    char* ws = (char*)d_ws;
    size_t off = 0;
    auto alloc = [&](size_t bytes) { void* p = ws + off; off = (off + bytes + 255) & ~(size_t)255; return p; };
    unsigned long long* pdeg = (unsigned long long*)alloc((size_t)N * 8);
    float* dinv   = (float*)alloc((size_t)N * 4);
    int*   cnt    = (int*)  alloc((size_t)N * 4);
    int*   rowptr = (int*)  alloc((size_t)(N + 1) * 4);
    int*   bsum   = (int*)  alloc((size_t)NB * 4);
    int*   rank   = (int*)  alloc((size_t)E * 4);
    int2*  spack  = (int2*) alloc((size_t)E * 8);
    __half* A     = (__half*)alloc((size_t)N * DIM * 2);   // H buffer (fp16)
    float* out    = (float*)d_out;

    dim3 blk(256);
    int gN  = (N + 255) / 256;
    int gE  = (E + 255) / 256;
    int gMM = (N + 127) / 128;          // 128 rows per block (2 threads/row)
    int gG  = (N + NPB - 1) / NPB;

    // ---- CSR build (once, shared by both layers) ----
    hipMemsetAsync(pdeg, 0, (size_t)N * 8, stream);
    edge_pack_kernel<<<gE, blk, 0, stream>>>(col, ew, pdeg, rank, E);
    to_dinv_kernel<<<gN, blk, 0, stream>>>(pdeg, dinv, cnt, N);
    scan_phaseA<<<NB, SCAN_BLK, 0, stream>>>(cnt, bsum, N);
    scan_phaseB<<<1, 1024, 0, stream>>>(bsum, rowptr, NB, N);
    scan_phaseC<<<NB, SCAN_BLK, 0, stream>>>(cnt, bsum, rowptr, N);
    fill_kernel<<<gE, blk, 0, stream>>>(row, col, ew, dinv, rowptr, rank, spack, E);

    // ---- layer 1 ----  (y1 goes into d_out as scratch)
    gemm96_kernel<<<gMM, blk, 0, stream>>>(x, W1, A, N);
    gather_kernel<<<gG, 192, 0, stream>>>(rowptr, spack, dinv, A, b1, out, N);

    // ---- layer 2 ----
    gemm96_kernel<<<gMM, blk, 0, stream>>>(out, W2, A, N);
    gather_kernel<<<gG, 192, 0, stream>>>(rowptr, spack, dinv, A, b2, out, N);
}

// Round 7
// 168.781 us; speedup vs baseline: 4.5075x; 1.3311x over previous
//
#include <hip/hip_runtime.h>
#include <hip/hip_fp16.h>

#define DIM 96
#define DIM4 (DIM/4)

typedef _Float16 f16x8 __attribute__((ext_vector_type(8)));
typedef float    f32x4 __attribute__((ext_vector_type(4)));

// ---------------- per-edge: packed (count<<32 | fixed-point weight) histogram ----------------
// weight scale 2^22; max weighted in-degree << 64 so low word stays < 2^28: no carry into count.
// Atomic return's high word = this edge's rank within its destination segment (replaces cursor).

#define WSCALE 4194304.0f   // 2^22

__global__ void edge_pack_kernel(const int* __restrict__ col, const float* __restrict__ ew,
                                 unsigned long long* __restrict__ pdeg,
                                 int* __restrict__ rank, int e) {
    int i = blockIdx.x * blockDim.x + threadIdx.x;
    if (i < e) {
        unsigned q = (unsigned)(ew[i] * WSCALE + 0.5f);
        unsigned long long old =
            atomicAdd(&pdeg[col[i]], (1ULL << 32) | (unsigned long long)q);
        rank[i] = (int)(old >> 32);
    }
}

// unpack: dinv = rsqrt(1 + wsum), cnt = count
__global__ void to_dinv_kernel(const unsigned long long* __restrict__ pdeg,
                               float* __restrict__ dinv, int* __restrict__ cnt, int n) {
    int i = blockIdx.x * blockDim.x + threadIdx.x;
    if (i < n) {
        unsigned long long p = pdeg[i];
        cnt[i] = (int)(p >> 32);
        float deg = 1.0f + (float)(p & 0xffffffffULL) * (1.0f / WSCALE);
        dinv[i] = rsqrtf(deg);
    }
}

// ---------------- W -> W^T fp16 (both layers) ----------------

__global__ void wprep_kernel(const float* __restrict__ W1, const float* __restrict__ W2,
                             _Float16* __restrict__ Bt1, _Float16* __restrict__ Bt2) {
    int i = blockIdx.x * blockDim.x + threadIdx.x;
    if (i < DIM * DIM) {
        int c = i / DIM, k = i - c * DIM;
        Bt1[i] = (_Float16)W1[k * DIM + c];
        Bt2[i] = (_Float16)W2[k * DIM + c];
    }
}

// ---------------- 3-phase multi-block exclusive scan: cnt -> rowptr ----------------

#define SCAN_BLK 256
#define SCAN_ELEMS 1024

__global__ __launch_bounds__(SCAN_BLK) void scan_phaseA(const int* __restrict__ cnt,
                                                        int* __restrict__ bsum, int n) {
    __shared__ int sdata[SCAN_BLK];
    int base = blockIdx.x * SCAN_ELEMS;
    int s = 0;
#pragma unroll
    for (int j = 0; j < 4; ++j) {
        int i = base + j * SCAN_BLK + (int)threadIdx.x;
        if (i < n) s += cnt[i];
    }
    sdata[threadIdx.x] = s;
    __syncthreads();
    for (int off = SCAN_BLK / 2; off > 0; off >>= 1) {
        if (threadIdx.x < (unsigned)off) sdata[threadIdx.x] += sdata[threadIdx.x + off];
        __syncthreads();
    }
    if (threadIdx.x == 0) bsum[blockIdx.x] = sdata[0];
}

__global__ __launch_bounds__(1024) void scan_phaseB(int* __restrict__ bsum,
                                                    int* __restrict__ rowptr, int nb, int n) {
    __shared__ int sdata[1024];
    int v = (threadIdx.x < (unsigned)nb) ? bsum[threadIdx.x] : 0;
    sdata[threadIdx.x] = v;
    __syncthreads();
    for (int off = 1; off < 1024; off <<= 1) {
        int t = (threadIdx.x >= (unsigned)off) ? sdata[threadIdx.x - off] : 0;
        __syncthreads();
        sdata[threadIdx.x] += t;
        __syncthreads();
    }
    if (threadIdx.x < (unsigned)nb) bsum[threadIdx.x] = sdata[threadIdx.x] - v;  // exclusive
    if (threadIdx.x == (unsigned)(nb - 1)) rowptr[n] = sdata[threadIdx.x];       // total
}

__global__ __launch_bounds__(SCAN_BLK) void scan_phaseC(const int* __restrict__ cnt,
                                                        const int* __restrict__ bsum,
                                                        int* __restrict__ rowptr, int n) {
    __shared__ int sdata[SCAN_BLK];
    int base = blockIdx.x * SCAN_ELEMS + (int)threadIdx.x * 4;
    int v[4];
#pragma unroll
    for (int j = 0; j < 4; ++j) v[j] = (base + j < n) ? cnt[base + j] : 0;
    int tsum = v[0] + v[1] + v[2] + v[3];
    sdata[threadIdx.x] = tsum;
    __syncthreads();
    for (int off = 1; off < SCAN_BLK; off <<= 1) {
        int t = (threadIdx.x >= (unsigned)off) ? sdata[threadIdx.x - off] : 0;
        __syncthreads();
        sdata[threadIdx.x] += t;
        __syncthreads();
    }
    int excl = bsum[blockIdx.x] + sdata[threadIdx.x] - tsum;
#pragma unroll
    for (int j = 0; j < 4; ++j) {
        if (base + j < n) rowptr[base + j] = excl;
        excl += v[j];
    }
}

// ---------------- fill CSR (atomic-free): spack[rowptr[col]+rank] = {row, ew*dinv[row]} ----------------

__global__ void fill_kernel(const int* __restrict__ row, const int* __restrict__ col,
                            const float* __restrict__ ew, const float* __restrict__ dinv,
                            const int* __restrict__ rowptr, const int* __restrict__ rank,
                            int2* __restrict__ spack, int e) {
    int i = blockIdx.x * blockDim.x + threadIdx.x;
    if (i < e) {
        int c = col[i];
        int r = row[i];
        int p = rowptr[c] + rank[i];
        spack[p] = make_int2(r, __float_as_int(ew[i] * dinv[r]));
    }
}

// ---------------- MFMA GEMM: H = A @ W  (A: n x 96 f32 or fp16, Bt = W^T fp16) ----------------
// 4 waves/block, 16 rows/wave, 96 cols/wave. No LDS; Wt (18KB) lives in L1.
// Fragment layouts (measured m89/m91): A: row=l&15, k=8*(l>>4)+j ; B: col=l&15, k=8*(l>>4)+j ;
// C/D: col=l&15, row=4*(l>>4)+j.

template<bool A_IS_F32>
__global__ __launch_bounds__(256) void gemm_mfma_kernel(const void* __restrict__ Av,
                                                        const _Float16* __restrict__ Bt,
                                                        _Float16* __restrict__ H, int n) {
    int wave = threadIdx.x >> 6;
    int lane = threadIdx.x & 63;
    int r0 = blockIdx.x * 64 + wave * 16;
    if (r0 >= n) return;   // wave-uniform

    int lrow = lane & 15;
    int lk   = (lane >> 4) << 3;        // 0,8,16,24
    int arow = r0 + lrow;
    if (arow > n - 1) arow = n - 1;     // clamp loads; stores guarded below

    const _Float16* Ah = (const _Float16*)Av;
    const float*    Af = (const float*)Av;

    f32x4 acc[6] = {};

#pragma unroll
    for (int ks = 0; ks < 3; ++ks) {
        int k0 = ks * 32 + lk;
        f16x8 a;
        if (A_IS_F32) {
            const float* ap = Af + (size_t)arow * DIM + k0;
            float4 x0 = *(const float4*)ap;
            float4 x1 = *(const float4*)(ap + 4);
            a[0] = (_Float16)x0.x; a[1] = (_Float16)x0.y;
            a[2] = (_Float16)x0.z; a[3] = (_Float16)x0.w;
            a[4] = (_Float16)x1.x; a[5] = (_Float16)x1.y;
            a[6] = (_Float16)x1.z; a[7] = (_Float16)x1.w;
        } else {
            a = *(const f16x8*)(Ah + (size_t)arow * DIM + k0);
        }
#pragma unroll
        for (int ct = 0; ct < 6; ++ct) {
            f16x8 b = *(const f16x8*)(Bt + (size_t)(ct * 16 + lrow) * DIM + k0);
            acc[ct] = __builtin_amdgcn_mfma_f32_16x16x32_f16(a, b, acc[ct], 0, 0, 0);
        }
    }

    int crow = r0 + ((lane >> 4) << 2);
    int ccol = lane & 15;
#pragma unroll
    for (int ct = 0; ct < 6; ++ct) {
#pragma unroll
        for (int j = 0; j < 4; ++j) {
            int rr = crow + j;
            if (rr < n) H[(size_t)rr * DIM + ct * 16 + ccol] = (_Float16)acc[ct][j];
        }
    }
}

// ---------------- fused gather + self-loop + bias + relu (H fp16; out fp16 or f32) ----------------
// 24 threads per node (each owns 4 features = 8 bytes), 8 nodes per 192-thread block.

#define NPB 8

__device__ __forceinline__ float4 half4_to_float4(uint2 hv) {
    __half2 h01 = *(const __half2*)&hv.x;
    __half2 h23 = *(const __half2*)&hv.y;
    float2 f01 = __half22float2(h01);
    float2 f23 = __half22float2(h23);
    return make_float4(f01.x, f01.y, f23.x, f23.y);
}

template<bool OUT_F32>
__global__ __launch_bounds__(192) void gather_kernel(const int* __restrict__ rowptr,
                                                     const int2* __restrict__ spack,
                                                     const float* __restrict__ dinv,
                                                     const __half* __restrict__ H,
                                                     const float* __restrict__ bias,
                                                     float* __restrict__ outf,
                                                     __half* __restrict__ outh, int n) {
    int ln = threadIdx.x / 24;
    int q  = threadIdx.x - ln * 24;
    int node = blockIdx.x * NPB + ln;
    if (node >= n) return;

    int beg = rowptr[node];
    int end = rowptr[node + 1];
    float di = dinv[node];

    float4 acc = make_float4(0.f, 0.f, 0.f, 0.f);
    int p = beg;
    for (; p + 1 < end; p += 2) {
        int2 e0 = spack[p];
        int2 e1 = spack[p + 1];
        float w0 = __int_as_float(e0.y) * di;
        float w1 = __int_as_float(e1.y) * di;
        uint2 hv0 = ((const uint2*)(H + (size_t)e0.x * DIM))[q];
        uint2 hv1 = ((const uint2*)(H + (size_t)e1.x * DIM))[q];
        float4 h0 = half4_to_float4(hv0);
        float4 h1 = half4_to_float4(hv1);
        acc.x = fmaf(w0, h0.x, acc.x); acc.y = fmaf(w0, h0.y, acc.y);
        acc.z = fmaf(w0, h0.z, acc.z); acc.w = fmaf(w0, h0.w, acc.w);
        acc.x = fmaf(w1, h1.x, acc.x); acc.y = fmaf(w1, h1.y, acc.y);
        acc.z = fmaf(w1, h1.z, acc.z); acc.w = fmaf(w1, h1.w, acc.w);
    }
    if (p < end) {
        int2 e0 = spack[p];
        float w0 = __int_as_float(e0.y) * di;
        float4 h0 = half4_to_float4(((const uint2*)(H + (size_t)e0.x * DIM))[q]);
        acc.x = fmaf(w0, h0.x, acc.x); acc.y = fmaf(w0, h0.y, acc.y);
        acc.z = fmaf(w0, h0.z, acc.z); acc.w = fmaf(w0, h0.w, acc.w);
    }

    float s = di * di;
    float4 hc = half4_to_float4(((const uint2*)(H + (size_t)node * DIM))[q]);
    float4 b  = ((const float4*)bias)[q];

    float4 o;
    o.x = fmaxf(fmaf(hc.x, s, acc.x) + b.x, 0.0f);
    o.y = fmaxf(fmaf(hc.y, s, acc.y) + b.y, 0.0f);
    o.z = fmaxf(fmaf(hc.z, s, acc.z) + b.z, 0.0f);
    o.w = fmaxf(fmaf(hc.w, s, acc.w) + b.w, 0.0f);

    if (OUT_F32) {
        ((float4*)(outf + (size_t)node * DIM))[q] = o;
    } else {
        __half2 lo = __float22half2_rn(make_float2(o.x, o.y));
        __half2 hi = __float22half2_rn(make_float2(o.z, o.w));
        uint2 u;
        u.x = *(const unsigned*)&lo;
        u.y = *(const unsigned*)&hi;
        ((uint2*)(outh + (size_t)node * DIM))[q] = u;
    }
}

// ---------------- launch ----------------

extern "C" void kernel_launch(void* const* d_in, const int* in_sizes, int n_in,
                              void* d_out, int out_size, void* d_ws, size_t ws_size,
                              hipStream_t stream) {
    const float* x   = (const float*)d_in[0];
    const int*   ei  = (const int*)d_in[1];
    const float* ew  = (const float*)d_in[2];
    // d_in[3] = batch (unused)
    const float* W1  = (const float*)d_in[4];
    const float* b1  = (const float*)d_in[5];
    const float* W2  = (const float*)d_in[6];
    const float* b2  = (const float*)d_in[7];

    const int N = in_sizes[0] / DIM;
    const int E = in_sizes[1] / 2;
    const int* row = ei;
    const int* col = ei + E;

    const int NB = (N + SCAN_ELEMS - 1) / SCAN_ELEMS;

    // workspace layout (all 256B-aligned)
    char* ws = (char*)d_ws;
    size_t off = 0;
    auto alloc = [&](size_t bytes) { void* p = ws + off; off = (off + bytes + 255) & ~(size_t)255; return p; };
    unsigned long long* pdeg = (unsigned long long*)alloc((size_t)N * 8);
    float* dinv   = (float*)alloc((size_t)N * 4);
    int*   cnt    = (int*)  alloc((size_t)N * 4);
    int*   rowptr = (int*)  alloc((size_t)(N + 1) * 4);
    int*   bsum   = (int*)  alloc((size_t)NB * 4);
    int*   rank   = (int*)  alloc((size_t)E * 4);
    int2*  spack  = (int2*) alloc((size_t)E * 8);
    _Float16* A   = (_Float16*)alloc((size_t)N * DIM * 2);   // H buffer (fp16)
    _Float16* y1h = (_Float16*)alloc((size_t)N * DIM * 2);   // layer-1 output (fp16)
    _Float16* Bt1 = (_Float16*)alloc((size_t)DIM * DIM * 2); // W1^T fp16
    _Float16* Bt2 = (_Float16*)alloc((size_t)DIM * DIM * 2); // W2^T fp16
    float* out    = (float*)d_out;

    dim3 blk(256);
    int gN  = (N + 255) / 256;
    int gE  = (E + 255) / 256;
    int gMM = (N + 63) / 64;            // 64 rows per block, 4 waves
    int gG  = (N + NPB - 1) / NPB;
    int gW  = (DIM * DIM + 255) / 256;

    // ---- CSR build (once, shared by both layers) ----
    hipMemsetAsync(pdeg, 0, (size_t)N * 8, stream);
    wprep_kernel<<<gW, blk, 0, stream>>>(W1, W2, Bt1, Bt2);
    edge_pack_kernel<<<gE, blk, 0, stream>>>(col, ew, pdeg, rank, E);
    to_dinv_kernel<<<gN, blk, 0, stream>>>(pdeg, dinv, cnt, N);
    scan_phaseA<<<NB, SCAN_BLK, 0, stream>>>(cnt, bsum, N);
    scan_phaseB<<<1, 1024, 0, stream>>>(bsum, rowptr, NB, N);
    scan_phaseC<<<NB, SCAN_BLK, 0, stream>>>(cnt, bsum, rowptr, N);
    fill_kernel<<<gE, blk, 0, stream>>>(row, col, ew, dinv, rowptr, rank, spack, E);

    // ---- layer 1 ----
    gemm_mfma_kernel<true><<<gMM, blk, 0, stream>>>(x, Bt1, A, N);
    gather_kernel<false><<<gG, 192, 0, stream>>>(rowptr, spack, dinv, (const __half*)A, b1,
                                                 nullptr, (__half*)y1h, N);

    // ---- layer 2 ----
    gemm_mfma_kernel<false><<<gMM, blk, 0, stream>>>(y1h, Bt2, A, N);
    gather_kernel<true><<<gG, 192, 0, stream>>>(rowptr, spack, dinv, (const __half*)A, b2,
                                                out, nullptr, N);
}

// Round 8
// 165.263 us; speedup vs baseline: 4.6034x; 1.0213x over previous
//
#include <hip/hip_runtime.h>
#include <hip/hip_fp16.h>

#define DIM 96
#define DIM4 (DIM/4)

typedef _Float16 f16x8 __attribute__((ext_vector_type(8)));
typedef float    f32x4 __attribute__((ext_vector_type(4)));

// pdeg padded: one u64 per 64B cache line (index i -> pdeg[i<<3]) to avoid
// per-line atomic serialization (8 nodes/line otherwise).
#define PDEG_SHIFT 3

#define WSCALE 4194304.0f   // 2^22

// ---------------- prep: zero padded pdeg + W->W^T fp16 (one launch) ----------------

#define PREP_BLOCKS 512

__global__ __launch_bounds__(256) void prep_kernel(unsigned long long* __restrict__ pdeg,
                                                   const float* __restrict__ W1,
                                                   const float* __restrict__ W2,
                                                   _Float16* __restrict__ Bt1,
                                                   _Float16* __restrict__ Bt2, int n) {
    int total = n << PDEG_SHIFT;
    for (int i = blockIdx.x * 256 + threadIdx.x; i < total; i += PREP_BLOCKS * 256)
        pdeg[i] = 0ULL;
    int i = blockIdx.x * 256 + threadIdx.x;
    if (i < DIM * DIM) {
        int c = i / DIM, k = i - c * DIM;
        Bt1[i] = (_Float16)W1[k * DIM + c];
        Bt2[i] = (_Float16)W2[k * DIM + c];
    }
}

// ---------------- per-edge: packed (count<<32 | fixed-point weight) histogram ----------------
// Atomic return's high word = this edge's rank within its destination segment.

__global__ void edge_pack_kernel(const int* __restrict__ col, const float* __restrict__ ew,
                                 unsigned long long* __restrict__ pdeg,
                                 int* __restrict__ rank, int e) {
    int i = blockIdx.x * blockDim.x + threadIdx.x;
    if (i < e) {
        unsigned q = (unsigned)(ew[i] * WSCALE + 0.5f);
        unsigned long long old =
            atomicAdd(&pdeg[(size_t)col[i] << PDEG_SHIFT], (1ULL << 32) | (unsigned long long)q);
        rank[i] = (int)(old >> 32);
    }
}

// unpack: dinv = rsqrt(1 + wsum), cnt = count
__global__ void to_dinv_kernel(const unsigned long long* __restrict__ pdeg,
                               float* __restrict__ dinv, int* __restrict__ cnt, int n) {
    int i = blockIdx.x * blockDim.x + threadIdx.x;
    if (i < n) {
        unsigned long long p = pdeg[(size_t)i << PDEG_SHIFT];
        cnt[i] = (int)(p >> 32);
        float deg = 1.0f + (float)(p & 0xffffffffULL) * (1.0f / WSCALE);
        dinv[i] = rsqrtf(deg);
    }
}

// ---------------- 3-phase multi-block exclusive scan: cnt -> rowptr ----------------

#define SCAN_BLK 256
#define SCAN_ELEMS 1024

__global__ __launch_bounds__(SCAN_BLK) void scan_phaseA(const int* __restrict__ cnt,
                                                        int* __restrict__ bsum, int n) {
    __shared__ int sdata[SCAN_BLK];
    int base = blockIdx.x * SCAN_ELEMS;
    int s = 0;
#pragma unroll
    for (int j = 0; j < 4; ++j) {
        int i = base + j * SCAN_BLK + (int)threadIdx.x;
        if (i < n) s += cnt[i];
    }
    sdata[threadIdx.x] = s;
    __syncthreads();
    for (int off = SCAN_BLK / 2; off > 0; off >>= 1) {
        if (threadIdx.x < (unsigned)off) sdata[threadIdx.x] += sdata[threadIdx.x + off];
        __syncthreads();
    }
    if (threadIdx.x == 0) bsum[blockIdx.x] = sdata[0];
}

__global__ __launch_bounds__(1024) void scan_phaseB(int* __restrict__ bsum,
                                                    int* __restrict__ rowptr, int nb, int n) {
    __shared__ int sdata[1024];
    int v = (threadIdx.x < (unsigned)nb) ? bsum[threadIdx.x] : 0;
    sdata[threadIdx.x] = v;
    __syncthreads();
    for (int off = 1; off < 1024; off <<= 1) {
        int t = (threadIdx.x >= (unsigned)off) ? sdata[threadIdx.x - off] : 0;
        __syncthreads();
        sdata[threadIdx.x] += t;
        __syncthreads();
    }
    if (threadIdx.x < (unsigned)nb) bsum[threadIdx.x] = sdata[threadIdx.x] - v;  // exclusive
    if (threadIdx.x == (unsigned)(nb - 1)) rowptr[n] = sdata[threadIdx.x];       // total
}

__global__ __launch_bounds__(SCAN_BLK) void scan_phaseC(const int* __restrict__ cnt,
                                                        const int* __restrict__ bsum,
                                                        int* __restrict__ rowptr, int n) {
    __shared__ int sdata[SCAN_BLK];
    int base = blockIdx.x * SCAN_ELEMS + (int)threadIdx.x * 4;
    int v[4];
#pragma unroll
    for (int j = 0; j < 4; ++j) v[j] = (base + j < n) ? cnt[base + j] : 0;
    int tsum = v[0] + v[1] + v[2] + v[3];
    sdata[threadIdx.x] = tsum;
    __syncthreads();
    for (int off = 1; off < SCAN_BLK; off <<= 1) {
        int t = (threadIdx.x >= (unsigned)off) ? sdata[threadIdx.x - off] : 0;
        __syncthreads();
        sdata[threadIdx.x] += t;
        __syncthreads();
    }
    int excl = bsum[blockIdx.x] + sdata[threadIdx.x] - tsum;
#pragma unroll
    for (int j = 0; j < 4; ++j) {
        if (base + j < n) rowptr[base + j] = excl;
        excl += v[j];
    }
}

// ---------------- fill CSR (atomic-free): spack[rowptr[col]+rank] = {row, ew*dinv[row]} ----------------

__global__ void fill_kernel(const int* __restrict__ row, const int* __restrict__ col,
                            const float* __restrict__ ew, const float* __restrict__ dinv,
                            const int* __restrict__ rowptr, const int* __restrict__ rank,
                            int2* __restrict__ spack, int e) {
    int i = blockIdx.x * blockDim.x + threadIdx.x;
    if (i < e) {
        int c = col[i];
        int r = row[i];
        int p = rowptr[c] + rank[i];
        spack[p] = make_int2(r, __float_as_int(ew[i] * dinv[r]));
    }
}

// ---------------- MFMA GEMM: H = A @ W  (A: n x 96 f32 or fp16, Bt = W^T fp16) ----------------
// 4 waves/block, 16 rows/wave, 96 cols/wave. No LDS; Wt (18KB) lives in L1.

template<bool A_IS_F32>
__global__ __launch_bounds__(256) void gemm_mfma_kernel(const void* __restrict__ Av,
                                                        const _Float16* __restrict__ Bt,
                                                        _Float16* __restrict__ H, int n) {
    int wave = threadIdx.x >> 6;
    int lane = threadIdx.x & 63;
    int r0 = blockIdx.x * 64 + wave * 16;
    if (r0 >= n) return;   // wave-uniform

    int lrow = lane & 15;
    int lk   = (lane >> 4) << 3;        // 0,8,16,24
    int arow = r0 + lrow;
    if (arow > n - 1) arow = n - 1;     // clamp loads; stores guarded below

    const _Float16* Ah = (const _Float16*)Av;
    const float*    Af = (const float*)Av;

    f32x4 acc[6] = {};

#pragma unroll
    for (int ks = 0; ks < 3; ++ks) {
        int k0 = ks * 32 + lk;
        f16x8 a;
        if (A_IS_F32) {
            const float* ap = Af + (size_t)arow * DIM + k0;
            float4 x0 = *(const float4*)ap;
            float4 x1 = *(const float4*)(ap + 4);
            a[0] = (_Float16)x0.x; a[1] = (_Float16)x0.y;
            a[2] = (_Float16)x0.z; a[3] = (_Float16)x0.w;
            a[4] = (_Float16)x1.x; a[5] = (_Float16)x1.y;
            a[6] = (_Float16)x1.z; a[7] = (_Float16)x1.w;
        } else {
            a = *(const f16x8*)(Ah + (size_t)arow * DIM + k0);
        }
#pragma unroll
        for (int ct = 0; ct < 6; ++ct) {
            f16x8 b = *(const f16x8*)(Bt + (size_t)(ct * 16 + lrow) * DIM + k0);
            acc[ct] = __builtin_amdgcn_mfma_f32_16x16x32_f16(a, b, acc[ct], 0, 0, 0);
        }
    }

    int crow = r0 + ((lane >> 4) << 2);
    int ccol = lane & 15;
#pragma unroll
    for (int ct = 0; ct < 6; ++ct) {
#pragma unroll
        for (int j = 0; j < 4; ++j) {
            int rr = crow + j;
            if (rr < n) H[(size_t)rr * DIM + ct * 16 + ccol] = (_Float16)acc[ct][j];
        }
    }
}

// ---------------- fused gather + self-loop + bias + relu (H fp16; out fp16 or f32) ----------------

#define NPB 8

__device__ __forceinline__ float4 half4_to_float4(uint2 hv) {
    __half2 h01 = *(const __half2*)&hv.x;
    __half2 h23 = *(const __half2*)&hv.y;
    float2 f01 = __half22float2(h01);
    float2 f23 = __half22float2(h23);
    return make_float4(f01.x, f01.y, f23.x, f23.y);
}

template<bool OUT_F32>
__global__ __launch_bounds__(192) void gather_kernel(const int* __restrict__ rowptr,
                                                     const int2* __restrict__ spack,
                                                     const float* __restrict__ dinv,
                                                     const __half* __restrict__ H,
                                                     const float* __restrict__ bias,
                                                     float* __restrict__ outf,
                                                     __half* __restrict__ outh, int n) {
    int ln = threadIdx.x / 24;
    int q  = threadIdx.x - ln * 24;
    int node = blockIdx.x * NPB + ln;
    if (node >= n) return;

    int beg = rowptr[node];
    int end = rowptr[node + 1];
    float di = dinv[node];

    float4 acc = make_float4(0.f, 0.f, 0.f, 0.f);
    int p = beg;
    for (; p + 1 < end; p += 2) {
        int2 e0 = spack[p];
        int2 e1 = spack[p + 1];
        float w0 = __int_as_float(e0.y) * di;
        float w1 = __int_as_float(e1.y) * di;
        uint2 hv0 = ((const uint2*)(H + (size_t)e0.x * DIM))[q];
        uint2 hv1 = ((const uint2*)(H + (size_t)e1.x * DIM))[q];
        float4 h0 = half4_to_float4(hv0);
        float4 h1 = half4_to_float4(hv1);
        acc.x = fmaf(w0, h0.x, acc.x); acc.y = fmaf(w0, h0.y, acc.y);
        acc.z = fmaf(w0, h0.z, acc.z); acc.w = fmaf(w0, h0.w, acc.w);
        acc.x = fmaf(w1, h1.x, acc.x); acc.y = fmaf(w1, h1.y, acc.y);
        acc.z = fmaf(w1, h1.z, acc.z); acc.w = fmaf(w1, h1.w, acc.w);
    }
    if (p < end) {
        int2 e0 = spack[p];
        float w0 = __int_as_float(e0.y) * di;
        float4 h0 = half4_to_float4(((const uint2*)(H + (size_t)e0.x * DIM))[q]);
        acc.x = fmaf(w0, h0.x, acc.x); acc.y = fmaf(w0, h0.y, acc.y);
        acc.z = fmaf(w0, h0.z, acc.z); acc.w = fmaf(w0, h0.w, acc.w);
    }

    float s = di * di;
    float4 hc = half4_to_float4(((const uint2*)(H + (size_t)node * DIM))[q]);
    float4 b  = ((const float4*)bias)[q];

    float4 o;
    o.x = fmaxf(fmaf(hc.x, s, acc.x) + b.x, 0.0f);
    o.y = fmaxf(fmaf(hc.y, s, acc.y) + b.y, 0.0f);
    o.z = fmaxf(fmaf(hc.z, s, acc.z) + b.z, 0.0f);
    o.w = fmaxf(fmaf(hc.w, s, acc.w) + b.w, 0.0f);

    if (OUT_F32) {
        ((float4*)(outf + (size_t)node * DIM))[q] = o;
    } else {
        __half2 lo = __float22half2_rn(make_float2(o.x, o.y));
        __half2 hi = __float22half2_rn(make_float2(o.z, o.w));
        uint2 u;
        u.x = *(const unsigned*)&lo;
        u.y = *(const unsigned*)&hi;
        ((uint2*)(outh + (size_t)node * DIM))[q] = u;
    }
}

// ---------------- launch ----------------

extern "C" void kernel_launch(void* const* d_in, const int* in_sizes, int n_in,
                              void* d_out, int out_size, void* d_ws, size_t ws_size,
                              hipStream_t stream) {
    const float* x   = (const float*)d_in[0];
    const int*   ei  = (const int*)d_in[1];
    const float* ew  = (const float*)d_in[2];
    // d_in[3] = batch (unused)
    const float* W1  = (const float*)d_in[4];
    const float* b1  = (const float*)d_in[5];
    const float* W2  = (const float*)d_in[6];
    const float* b2  = (const float*)d_in[7];

    const int N = in_sizes[0] / DIM;
    const int E = in_sizes[1] / 2;
    const int* row = ei;
    const int* col = ei + E;

    const int NB = (N + SCAN_ELEMS - 1) / SCAN_ELEMS;

    // workspace layout (all 256B-aligned)
    char* ws = (char*)d_ws;
    size_t off = 0;
    auto alloc = [&](size_t bytes) { void* p = ws + off; off = (off + bytes + 255) & ~(size_t)255; return p; };
    unsigned long long* pdeg = (unsigned long long*)alloc(((size_t)N << PDEG_SHIFT) * 8); // padded
    float* dinv   = (float*)alloc((size_t)N * 4);
    int*   cnt    = (int*)  alloc((size_t)N * 4);
    int*   rowptr = (int*)  alloc((size_t)(N + 1) * 4);
    int*   bsum   = (int*)  alloc((size_t)NB * 4);
    int*   rank   = (int*)  alloc((size_t)E * 4);
    int2*  spack  = (int2*) alloc((size_t)E * 8);
    _Float16* A   = (_Float16*)alloc((size_t)N * DIM * 2);   // H buffer (fp16)
    _Float16* y1h = (_Float16*)alloc((size_t)N * DIM * 2);   // layer-1 output (fp16)
    _Float16* Bt1 = (_Float16*)alloc((size_t)DIM * DIM * 2); // W1^T fp16
    _Float16* Bt2 = (_Float16*)alloc((size_t)DIM * DIM * 2); // W2^T fp16
    float* out    = (float*)d_out;

    dim3 blk(256);
    int gN  = (N + 255) / 256;
    int gE  = (E + 255) / 256;
    int gMM = (N + 63) / 64;            // 64 rows per block, 4 waves
    int gG  = (N + NPB - 1) / NPB;

    // ---- CSR build (once, shared by both layers) ----
    prep_kernel<<<PREP_BLOCKS, blk, 0, stream>>>(pdeg, W1, W2, Bt1, Bt2, N);
    edge_pack_kernel<<<gE, blk, 0, stream>>>(col, ew, pdeg, rank, E);
    to_dinv_kernel<<<gN, blk, 0, stream>>>(pdeg, dinv, cnt, N);
    scan_phaseA<<<NB, SCAN_BLK, 0, stream>>>(cnt, bsum, N);
    scan_phaseB<<<1, 1024, 0, stream>>>(bsum, rowptr, NB, N);
    scan_phaseC<<<NB, SCAN_BLK, 0, stream>>>(cnt, bsum, rowptr, N);
    fill_kernel<<<gE, blk, 0, stream>>>(row, col, ew, dinv, rowptr, rank, spack, E);

    // ---- layer 1 ----
    gemm_mfma_kernel<true><<<gMM, blk, 0, stream>>>(x, Bt1, A, N);
    gather_kernel<false><<<gG, 192, 0, stream>>>(rowptr, spack, dinv, (const __half*)A, b1,
                                                 nullptr, (__half*)y1h, N);

    // ---- layer 2 ----
    gemm_mfma_kernel<false><<<gMM, blk, 0, stream>>>(y1h, Bt2, A, N);
    gather_kernel<true><<<gG, 192, 0, stream>>>(rowptr, spack, dinv, (const __half*)A, b2,
                                                out, nullptr, N);
}

// Round 9
// 157.395 us; speedup vs baseline: 4.8335x; 1.0500x over previous
//
#include <hip/hip_runtime.h>
#include <hip/hip_fp16.h>

#define DIM 96
#define DIM4 (DIM/4)

typedef _Float16 f16x8 __attribute__((ext_vector_type(8)));
typedef float    f32x4 __attribute__((ext_vector_type(4)));

#define WSCALE 4194304.0f   // 2^22

// ---------------- prep: zero pdeg + W->W^T fp16 (one launch) ----------------

#define PREP_BLOCKS 256

__global__ __launch_bounds__(256) void prep_kernel(unsigned long long* __restrict__ pdeg,
                                                   const float* __restrict__ W1,
                                                   const float* __restrict__ W2,
                                                   _Float16* __restrict__ Bt1,
                                                   _Float16* __restrict__ Bt2, int n) {
    for (int i = blockIdx.x * 256 + threadIdx.x; i < n; i += PREP_BLOCKS * 256)
        pdeg[i] = 0ULL;
    int i = blockIdx.x * 256 + threadIdx.x;
    if (i < DIM * DIM) {
        int c = i / DIM, k = i - c * DIM;
        Bt1[i] = (_Float16)W1[k * DIM + c];
        Bt2[i] = (_Float16)W2[k * DIM + c];
    }
}

// ---------------- per-edge: packed (count<<32 | fixed-point weight) histogram ----------------
// Atomic return's high word = this edge's rank within its destination segment.

__global__ void edge_pack_kernel(const int* __restrict__ col, const float* __restrict__ ew,
                                 unsigned long long* __restrict__ pdeg,
                                 int* __restrict__ rank, int e) {
    int i = blockIdx.x * blockDim.x + threadIdx.x;
    if (i < e) {
        unsigned q = (unsigned)(ew[i] * WSCALE + 0.5f);
        unsigned long long old =
            atomicAdd(&pdeg[col[i]], (1ULL << 32) | (unsigned long long)q);
        rank[i] = (int)(old >> 32);
    }
}

// ---------------- fused unpack + scanA: dinv, cnt, per-1024-block sums ----------------

#define SCAN_BLK 256
#define SCAN_ELEMS 1024

__global__ __launch_bounds__(SCAN_BLK) void dinv_scanA_kernel(const unsigned long long* __restrict__ pdeg,
                                                              float* __restrict__ dinv,
                                                              int* __restrict__ cnt,
                                                              int* __restrict__ bsum, int n) {
    __shared__ int sdata[SCAN_BLK];
    int base = blockIdx.x * SCAN_ELEMS;
    int s = 0;
#pragma unroll
    for (int j = 0; j < 4; ++j) {
        int i = base + j * SCAN_BLK + (int)threadIdx.x;
        if (i < n) {
            unsigned long long p = pdeg[i];
            int c = (int)(p >> 32);
            cnt[i] = c;
            s += c;
            float deg = 1.0f + (float)(p & 0xffffffffULL) * (1.0f / WSCALE);
            dinv[i] = rsqrtf(deg);
        }
    }
    sdata[threadIdx.x] = s;
    __syncthreads();
    for (int off = SCAN_BLK / 2; off > 0; off >>= 1) {
        if (threadIdx.x < (unsigned)off) sdata[threadIdx.x] += sdata[threadIdx.x + off];
        __syncthreads();
    }
    if (threadIdx.x == 0) bsum[blockIdx.x] = sdata[0];
}

__global__ __launch_bounds__(1024) void scan_phaseB(int* __restrict__ bsum,
                                                    int* __restrict__ rowptr, int nb, int n) {
    __shared__ int sdata[1024];
    int v = (threadIdx.x < (unsigned)nb) ? bsum[threadIdx.x] : 0;
    sdata[threadIdx.x] = v;
    __syncthreads();
    for (int off = 1; off < 1024; off <<= 1) {
        int t = (threadIdx.x >= (unsigned)off) ? sdata[threadIdx.x - off] : 0;
        __syncthreads();
        sdata[threadIdx.x] += t;
        __syncthreads();
    }
    if (threadIdx.x < (unsigned)nb) bsum[threadIdx.x] = sdata[threadIdx.x] - v;  // exclusive
    if (threadIdx.x == (unsigned)(nb - 1)) rowptr[n] = sdata[threadIdx.x];       // total
}

__global__ __launch_bounds__(SCAN_BLK) void scan_phaseC(const int* __restrict__ cnt,
                                                        const int* __restrict__ bsum,
                                                        int* __restrict__ rowptr, int n) {
    __shared__ int sdata[SCAN_BLK];
    int base = blockIdx.x * SCAN_ELEMS + (int)threadIdx.x * 4;
    int v[4];
#pragma unroll
    for (int j = 0; j < 4; ++j) v[j] = (base + j < n) ? cnt[base + j] : 0;
    int tsum = v[0] + v[1] + v[2] + v[3];
    sdata[threadIdx.x] = tsum;
    __syncthreads();
    for (int off = 1; off < SCAN_BLK; off <<= 1) {
        int t = (threadIdx.x >= (unsigned)off) ? sdata[threadIdx.x - off] : 0;
        __syncthreads();
        sdata[threadIdx.x] += t;
        __syncthreads();
    }
    int excl = bsum[blockIdx.x] + sdata[threadIdx.x] - tsum;
#pragma unroll
    for (int j = 0; j < 4; ++j) {
        if (base + j < n) rowptr[base + j] = excl;
        excl += v[j];
    }
}

// ---------------- fill CSR (atomic-free): spack[rowptr[col]+rank] = {row, ew*dinv[row]} ----------------

__global__ void fill_kernel(const int* __restrict__ row, const int* __restrict__ col,
                            const float* __restrict__ ew, const float* __restrict__ dinv,
                            const int* __restrict__ rowptr, const int* __restrict__ rank,
                            int2* __restrict__ spack, int e) {
    int i = blockIdx.x * blockDim.x + threadIdx.x;
    if (i < e) {
        int c = col[i];
        int r = row[i];
        int p = rowptr[c] + rank[i];
        spack[p] = make_int2(r, __float_as_int(ew[i] * dinv[r]));
    }
}

// ---------------- MFMA GEMM: H = A @ W  (A: n x 96 f32 or fp16, Bt = W^T fp16) ----------------
// 4 waves/block, 16 rows/wave, 96 cols/wave. No LDS; Wt (18KB) lives in L1.

template<bool A_IS_F32>
__global__ __launch_bounds__(256) void gemm_mfma_kernel(const void* __restrict__ Av,
                                                        const _Float16* __restrict__ Bt,
                                                        _Float16* __restrict__ H, int n) {
    int wave = threadIdx.x >> 6;
    int lane = threadIdx.x & 63;
    int r0 = blockIdx.x * 64 + wave * 16;
    if (r0 >= n) return;   // wave-uniform

    int lrow = lane & 15;
    int lk   = (lane >> 4) << 3;        // 0,8,16,24
    int arow = r0 + lrow;
    if (arow > n - 1) arow = n - 1;     // clamp loads; stores guarded below

    const _Float16* Ah = (const _Float16*)Av;
    const float*    Af = (const float*)Av;

    f32x4 acc[6] = {};

#pragma unroll
    for (int ks = 0; ks < 3; ++ks) {
        int k0 = ks * 32 + lk;
        f16x8 a;
        if (A_IS_F32) {
            const float* ap = Af + (size_t)arow * DIM + k0;
            float4 x0 = *(const float4*)ap;
            float4 x1 = *(const float4*)(ap + 4);
            a[0] = (_Float16)x0.x; a[1] = (_Float16)x0.y;
            a[2] = (_Float16)x0.z; a[3] = (_Float16)x0.w;
            a[4] = (_Float16)x1.x; a[5] = (_Float16)x1.y;
            a[6] = (_Float16)x1.z; a[7] = (_Float16)x1.w;
        } else {
            a = *(const f16x8*)(Ah + (size_t)arow * DIM + k0);
        }
#pragma unroll
        for (int ct = 0; ct < 6; ++ct) {
            f16x8 b = *(const f16x8*)(Bt + (size_t)(ct * 16 + lrow) * DIM + k0);
            acc[ct] = __builtin_amdgcn_mfma_f32_16x16x32_f16(a, b, acc[ct], 0, 0, 0);
        }
    }

    int crow = r0 + ((lane >> 4) << 2);
    int ccol = lane & 15;
#pragma unroll
    for (int ct = 0; ct < 6; ++ct) {
#pragma unroll
        for (int j = 0; j < 4; ++j) {
            int rr = crow + j;
            if (rr < n) H[(size_t)rr * DIM + ct * 16 + ccol] = (_Float16)acc[ct][j];
        }
    }
}

// ---------------- fused gather + self-loop + bias + relu (H fp16; out fp16 or f32) ----------------
// 24 threads per node (8B each = 192B row), 4-edge chunks for 4 independent row loads in flight.

#define NPB 8

__device__ __forceinline__ float4 half4_to_float4(uint2 hv) {
    __half2 h01 = *(const __half2*)&hv.x;
    __half2 h23 = *(const __half2*)&hv.y;
    float2 f01 = __half22float2(h01);
    float2 f23 = __half22float2(h23);
    return make_float4(f01.x, f01.y, f23.x, f23.y);
}

template<bool OUT_F32>
__global__ __launch_bounds__(192) void gather_kernel(const int* __restrict__ rowptr,
                                                     const int2* __restrict__ spack,
                                                     const float* __restrict__ dinv,
                                                     const __half* __restrict__ H,
                                                     const float* __restrict__ bias,
                                                     float* __restrict__ outf,
                                                     __half* __restrict__ outh, int n) {
    int ln = threadIdx.x / 24;
    int q  = threadIdx.x - ln * 24;
    int node = blockIdx.x * NPB + ln;
    if (node >= n) return;

    int beg = rowptr[node];
    int end = rowptr[node + 1];
    float di = dinv[node];

    const uint2* Hq = (const uint2*)H;   // 8B units; index = row*24 + q

    float4 acc = make_float4(0.f, 0.f, 0.f, 0.f);
    int p = beg;
    for (; p + 3 < end; p += 4) {
        int2 e0 = spack[p];
        int2 e1 = spack[p + 1];
        int2 e2 = spack[p + 2];
        int2 e3 = spack[p + 3];
        uint2 v0 = Hq[e0.x * 24 + q];
        uint2 v1 = Hq[e1.x * 24 + q];
        uint2 v2 = Hq[e2.x * 24 + q];
        uint2 v3 = Hq[e3.x * 24 + q];
        float w0 = __int_as_float(e0.y);
        float w1 = __int_as_float(e1.y);
        float w2 = __int_as_float(e2.y);
        float w3 = __int_as_float(e3.y);
        float4 h0 = half4_to_float4(v0);
        float4 h1 = half4_to_float4(v1);
        float4 h2 = half4_to_float4(v2);
        float4 h3 = half4_to_float4(v3);
        acc.x = fmaf(w0, h0.x, acc.x); acc.y = fmaf(w0, h0.y, acc.y);
        acc.z = fmaf(w0, h0.z, acc.z); acc.w = fmaf(w0, h0.w, acc.w);
        acc.x = fmaf(w1, h1.x, acc.x); acc.y = fmaf(w1, h1.y, acc.y);
        acc.z = fmaf(w1, h1.z, acc.z); acc.w = fmaf(w1, h1.w, acc.w);
        acc.x = fmaf(w2, h2.x, acc.x); acc.y = fmaf(w2, h2.y, acc.y);
        acc.z = fmaf(w2, h2.z, acc.z); acc.w = fmaf(w2, h2.w, acc.w);
        acc.x = fmaf(w3, h3.x, acc.x); acc.y = fmaf(w3, h3.y, acc.y);
        acc.z = fmaf(w3, h3.z, acc.z); acc.w = fmaf(w3, h3.w, acc.w);
    }
    for (; p < end; ++p) {
        int2 e0 = spack[p];
        float w0 = __int_as_float(e0.y);
        float4 h0 = half4_to_float4(Hq[e0.x * 24 + q]);
        acc.x = fmaf(w0, h0.x, acc.x); acc.y = fmaf(w0, h0.y, acc.y);
        acc.z = fmaf(w0, h0.z, acc.z); acc.w = fmaf(w0, h0.w, acc.w);
    }

    float s = di * di;
    float4 hc = half4_to_float4(Hq[node * 24 + q]);
    float4 b  = ((const float4*)bias)[q];

    float4 o;
    o.x = fmaxf(fmaf(hc.x, s, fmaf(acc.x, di, 0.f)) + b.x, 0.0f);
    o.y = fmaxf(fmaf(hc.y, s, fmaf(acc.y, di, 0.f)) + b.y, 0.0f);
    o.z = fmaxf(fmaf(hc.z, s, fmaf(acc.z, di, 0.f)) + b.z, 0.0f);
    o.w = fmaxf(fmaf(hc.w, s, fmaf(acc.w, di, 0.f)) + b.w, 0.0f);

    if (OUT_F32) {
        ((float4*)(outf + (size_t)node * DIM))[q] = o;
    } else {
        __half2 lo = __float22half2_rn(make_float2(o.x, o.y));
        __half2 hi = __float22half2_rn(make_float2(o.z, o.w));
        uint2 u;
        u.x = *(const unsigned*)&lo;
        u.y = *(const unsigned*)&hi;
        ((uint2*)(outh + (size_t)node * DIM))[q] = u;
    }
}

// ---------------- launch ----------------

extern "C" void kernel_launch(void* const* d_in, const int* in_sizes, int n_in,
                              void* d_out, int out_size, void* d_ws, size_t ws_size,
                              hipStream_t stream) {
    const float* x   = (const float*)d_in[0];
    const int*   ei  = (const int*)d_in[1];
    const float* ew  = (const float*)d_in[2];
    // d_in[3] = batch (unused)
    const float* W1  = (const float*)d_in[4];
    const float* b1  = (const float*)d_in[5];
    const float* W2  = (const float*)d_in[6];
    const float* b2  = (const float*)d_in[7];

    const int N = in_sizes[0] / DIM;
    const int E = in_sizes[1] / 2;
    const int* row = ei;
    const int* col = ei + E;

    const int NB = (N + SCAN_ELEMS - 1) / SCAN_ELEMS;

    // workspace layout (all 256B-aligned)
    char* ws = (char*)d_ws;
    size_t off = 0;
    auto alloc = [&](size_t bytes) { void* p = ws + off; off = (off + bytes + 255) & ~(size_t)255; return p; };
    unsigned long long* pdeg = (unsigned long long*)alloc((size_t)N * 8);
    float* dinv   = (float*)alloc((size_t)N * 4);
    int*   cnt    = (int*)  alloc((size_t)N * 4);
    int*   rowptr = (int*)  alloc((size_t)(N + 1) * 4);
    int*   bsum   = (int*)  alloc((size_t)NB * 4);
    int*   rank   = (int*)  alloc((size_t)E * 4);
    int2*  spack  = (int2*) alloc((size_t)E * 8);
    _Float16* A   = (_Float16*)alloc((size_t)N * DIM * 2);   // H buffer (fp16)
    _Float16* y1h = (_Float16*)alloc((size_t)N * DIM * 2);   // layer-1 output (fp16)
    _Float16* Bt1 = (_Float16*)alloc((size_t)DIM * DIM * 2); // W1^T fp16
    _Float16* Bt2 = (_Float16*)alloc((size_t)DIM * DIM * 2); // W2^T fp16
    float* out    = (float*)d_out;

    dim3 blk(256);
    int gE  = (E + 255) / 256;
    int gMM = (N + 63) / 64;            // 64 rows per block, 4 waves
    int gG  = (N + NPB - 1) / NPB;

    // ---- CSR build (once, shared by both layers) ----
    prep_kernel<<<PREP_BLOCKS, blk, 0, stream>>>(pdeg, W1, W2, Bt1, Bt2, N);
    edge_pack_kernel<<<gE, blk, 0, stream>>>(col, ew, pdeg, rank, E);
    dinv_scanA_kernel<<<NB, SCAN_BLK, 0, stream>>>(pdeg, dinv, cnt, bsum, N);
    scan_phaseB<<<1, 1024, 0, stream>>>(bsum, rowptr, NB, N);
    scan_phaseC<<<NB, SCAN_BLK, 0, stream>>>(cnt, bsum, rowptr, N);
    fill_kernel<<<gE, blk, 0, stream>>>(row, col, ew, dinv, rowptr, rank, spack, E);

    // ---- layer 1 ----
    gemm_mfma_kernel<true><<<gMM, blk, 0, stream>>>(x, Bt1, A, N);
    gather_kernel<false><<<gG, 192, 0, stream>>>(rowptr, spack, dinv, (const __half*)A, b1,
                                                 nullptr, (__half*)y1h, N);

    // ---- layer 2 ----
    gemm_mfma_kernel<false><<<gMM, blk, 0, stream>>>(y1h, Bt2, A, N);
    gather_kernel<true><<<gG, 192, 0, stream>>>(rowptr, spack, dinv, (const __half*)A, b2,
                                                out, nullptr, N);
}